// Round 1
// baseline (8011.854 us; speedup 1.0000x reference)
//
#include <hip/hip_runtime.h>
#include <math.h>

// ---------------- block reduction helpers (blockDim multiple of 64) ----------------
__device__ __forceinline__ float block_sum(float v, float* sdata) {
#pragma unroll
  for (int o = 32; o > 0; o >>= 1) v += __shfl_down(v, o, 64);
  __syncthreads();
  int lane = threadIdx.x & 63, wid = threadIdx.x >> 6;
  if (lane == 0) sdata[wid] = v;
  __syncthreads();
  float s = 0.f;
  int nw = blockDim.x >> 6;
  for (int i = 0; i < nw; i++) s += sdata[i];
  return s;
}

__device__ __forceinline__ float block_max(float v, float* sdata) {
#pragma unroll
  for (int o = 32; o > 0; o >>= 1) v = fmaxf(v, __shfl_down(v, o, 64));
  __syncthreads();
  int lane = threadIdx.x & 63, wid = threadIdx.x >> 6;
  if (lane == 0) sdata[wid] = v;
  __syncthreads();
  float m = -INFINITY;
  int nw = blockDim.x >> 6;
  for (int i = 0; i < nw; i++) m = fmaxf(m, sdata[i]);
  return m;
}

// ---------------- z = norm(embed[masked]); xsa = z ----------------
// norm(x) = x / (1 + std(x, ddof=1)); one block per row, blockDim = E
__global__ void embed_norm_kernel(const int* __restrict__ masked,
                                  const float* __restrict__ embed,
                                  float* __restrict__ z, float* __restrict__ xsa, int E) {
  int row = blockIdx.x;
  int g = masked[row];
  __shared__ float sdata[8];
  float x = embed[(size_t)g * E + threadIdx.x];
  float mean = block_sum(x, sdata) / E;
  float d = x - mean;
  float var = block_sum(d * d, sdata) / (E - 1);
  float val = x / (1.0f + sqrtf(var));
  z[(size_t)row * E + threadIdx.x] = val;
  xsa[(size_t)row * E + threadIdx.x] = val;
}

// ---------------- generic fp32 GEMM ----------------
// C[m,n] = alpha * sum_k A(m,k) * W(.,.) [+ bias[n]] [+ C old if beta] [relu]
// TRANSA=0: A(m,k) = A[rowmap(m)*lda + k], rowmap applies per-batch roll of L rows
// TRANSA=1: A(m,k) = A[k*lda + m]   (shift ignored)
// TRANSW=0: W(k,n) = W[k*ldw + n];  TRANSW=1: W(n,k) = W[n*ldw + k]
// Tile 64x64x16, 256 threads, 4x4 per thread. All dims assumed multiples of tile.
template <int TRANSA, int TRANSW>
__global__ __launch_bounds__(256) void gemm_kernel(
    const float* __restrict__ A, int lda,
    const float* __restrict__ W, int ldw,
    const float* __restrict__ bias,
    float* __restrict__ C, int ldc,
    int K, float alpha, int beta, int relu, int shift, int Lroll) {
  __shared__ float As[16][64];
  __shared__ float Bs[16][64];
  int m0 = blockIdx.y * 64, n0 = blockIdx.x * 64;
  int tid = threadIdx.x;
  int tx = tid & 15, ty = tid >> 4;
  float acc[4][4] = {};
  for (int k0 = 0; k0 < K; k0 += 16) {
#pragma unroll
    for (int r = 0; r < 4; r++) {
      int idx = tid + r * 256;
      if (TRANSA) {
        int i = idx & 63, j = idx >> 6;
        As[j][i] = A[(size_t)(k0 + j) * lda + m0 + i];
      } else {
        int i = idx >> 4, j = idx & 15;
        int m = m0 + i;
        if (shift != 0) {
          int b = m / Lroll, l = m - b * Lroll;
          m = b * Lroll + ((l + shift + Lroll) % Lroll);
        }
        As[j][i] = A[(size_t)m * lda + k0 + j];
      }
    }
#pragma unroll
    for (int r = 0; r < 4; r++) {
      int idx = tid + r * 256;
      if (TRANSW) {
        int n = idx >> 4, j = idx & 15;
        Bs[j][n] = W[(size_t)(n0 + n) * ldw + k0 + j];
      } else {
        int n = idx & 63, j = idx >> 6;
        Bs[j][n] = W[(size_t)(k0 + j) * ldw + n0 + n];
      }
    }
    __syncthreads();
#pragma unroll
    for (int j = 0; j < 16; j++) {
      float a[4], b[4];
#pragma unroll
      for (int r = 0; r < 4; r++) a[r] = As[j][ty * 4 + r];
#pragma unroll
      for (int c = 0; c < 4; c++) b[c] = Bs[j][tx * 4 + c];
#pragma unroll
      for (int r = 0; r < 4; r++)
#pragma unroll
        for (int c = 0; c < 4; c++) acc[r][c] += a[r] * b[c];
    }
    __syncthreads();
  }
#pragma unroll
  for (int r = 0; r < 4; r++) {
    int m = m0 + ty * 4 + r;
#pragma unroll
    for (int c = 0; c < 4; c++) {
      int n = n0 + tx * 4 + c;
      float v = alpha * acc[r][c];
      if (bias) v += bias[n];
      if (beta) v += C[(size_t)m * ldc + n];
      if (relu) v = fmaxf(v, 0.f);
      C[(size_t)m * ldc + n] = v;
    }
  }
}

// ---------------- row softmax (in place), one block per row ----------------
__global__ void softmax_kernel(float* __restrict__ h, int cols) {
  int row = blockIdx.x;
  float* p = h + (size_t)row * cols;
  __shared__ float sdata[8];
  float m = -INFINITY;
  for (int c = threadIdx.x; c < cols; c += blockDim.x) m = fmaxf(m, p[c]);
  m = block_max(m, sdata);
  float s = 0.f;
  for (int c = threadIdx.x; c < cols; c += blockDim.x) {
    float e = expf(p[c] - m);
    p[c] = e;
    s += e;
  }
  s = block_sum(s, sdata);
  float inv = 1.f / s;
  for (int c = threadIdx.x; c < cols; c += blockDim.x) p[c] *= inv;
}

// ---------------- xsad=norm(xsad+xid); xsa=norm(xsa+0.05*xsad) -------------
__global__ void addnorm_kernel(const float* __restrict__ xsad,
                               const float* __restrict__ xid,
                               float* __restrict__ xsa, int E) {
  int row = blockIdx.x, t = threadIdx.x;
  __shared__ float sdata[8];
  size_t off = (size_t)row * E + t;
  float s1 = xsad[off] + xid[off];
  float mean = block_sum(s1, sdata) / E;
  float d = s1 - mean;
  float var = block_sum(d * d, sdata) / (E - 1);
  float n1 = s1 / (1.f + sqrtf(var));
  float t2 = xsa[off] + 0.05f * n1;
  float mean2 = block_sum(t2, sdata) / E;
  float d2 = t2 - mean2;
  float var2 = block_sum(d2 * d2, sdata) / (E - 1);
  xsa[off] = t2 / (1.f + sqrtf(var2));
}

// ---------------- gather masked positions + targets ----------------
__global__ void gather_kernel(const float* __restrict__ xsa, const int* __restrict__ mask,
                              const int* __restrict__ unmasked,
                              float* __restrict__ lptok, int* __restrict__ tgt,
                              int L, int LM, int E) {
  int bi = blockIdx.x;  // b*LM + i
  int b = bi / LM;
  int pos = mask[bi];
  lptok[(size_t)bi * E + threadIdx.x] = xsa[((size_t)b * L + pos) * E + threadIdx.x];
  if (threadIdx.x == 0) tgt[bi] = unmasked[b * L + pos];
}

// ---------------- head: per (row, 64-col chunk) logit stats ----------------
// logits[r,g] = dot(V[r,:], embed[g,:]); emit chunk max and sumexp(l - max)
__global__ __launch_bounds__(256) void head_stats_kernel(
    const float* __restrict__ V, const float* __restrict__ embed,
    float* __restrict__ statsM, float* __restrict__ statsS, int Kd, int nch) {
  __shared__ float As[16][64];
  __shared__ float Bs[16][64];
  int m0 = blockIdx.y * 64, n0 = blockIdx.x * 64;
  int tid = threadIdx.x;
  int tx = tid & 15, ty = tid >> 4;
  float acc[4][4] = {};
  for (int k0 = 0; k0 < Kd; k0 += 16) {
#pragma unroll
    for (int r = 0; r < 4; r++) {
      int idx = tid + r * 256;
      int i = idx >> 4, j = idx & 15;
      As[j][i] = V[(size_t)(m0 + i) * Kd + k0 + j];
      Bs[j][i] = embed[(size_t)(n0 + i) * Kd + k0 + j];
    }
    __syncthreads();
#pragma unroll
    for (int j = 0; j < 16; j++) {
      float a[4], b[4];
#pragma unroll
      for (int r = 0; r < 4; r++) a[r] = As[j][ty * 4 + r];
#pragma unroll
      for (int c = 0; c < 4; c++) b[c] = Bs[j][tx * 4 + c];
#pragma unroll
      for (int r = 0; r < 4; r++)
#pragma unroll
        for (int c = 0; c < 4; c++) acc[r][c] += a[r] * b[c];
    }
    __syncthreads();
  }
  __shared__ float red[64][17];
  __shared__ float rowmax[64];
#pragma unroll
  for (int r = 0; r < 4; r++) {
    float lm = fmaxf(fmaxf(acc[r][0], acc[r][1]), fmaxf(acc[r][2], acc[r][3]));
    red[ty * 4 + r][tx] = lm;
  }
  __syncthreads();
  if (tid < 64) {
    float m = -INFINITY;
    for (int j = 0; j < 16; j++) m = fmaxf(m, red[tid][j]);
    rowmax[tid] = m;
  }
  __syncthreads();
#pragma unroll
  for (int r = 0; r < 4; r++) {
    float rm = rowmax[ty * 4 + r];
    float s = 0.f;
#pragma unroll
    for (int c = 0; c < 4; c++) s += expf(acc[r][c] - rm);
    red[ty * 4 + r][tx] = s;
  }
  __syncthreads();
  if (tid < 64) {
    float s = 0.f;
    for (int j = 0; j < 16; j++) s += red[tid][j];
    int rowg = m0 + tid;
    statsM[(size_t)rowg * nch + blockIdx.x] = rowmax[tid];
    statsS[(size_t)rowg * nch + blockIdx.x] = s;
  }
}

// ---------------- combine chunk stats -> lse per row ----------------
__global__ void lse_reduce_kernel(const float* __restrict__ statsM,
                                  const float* __restrict__ statsS,
                                  float* __restrict__ lse, int nch) {
  int row = blockIdx.x, t = threadIdx.x;
  float m = -INFINITY, s = 0.f;
  for (int c = t; c < nch; c += blockDim.x) {
    float cm = statsM[(size_t)row * nch + c];
    float cs = statsS[(size_t)row * nch + c];
    float M = fmaxf(m, cm);
    s = s * expf(m - M) + cs * expf(cm - M);
    m = M;
  }
  __shared__ float sm[256], ss[256];
  sm[t] = m;
  ss[t] = s;
  __syncthreads();
  for (int o = 128; o > 0; o >>= 1) {
    if (t < o) {
      float m2 = sm[t + o], s2 = ss[t + o];
      float M = fmaxf(sm[t], m2);
      float sc = ss[t] * expf(sm[t] - M) + s2 * expf(m2 - M);
      sm[t] = M;
      ss[t] = sc;
    }
    __syncthreads();
  }
  if (t == 0) lse[row] = sm[0] + logf(ss[0]);
}

// ---------------- logit at target: lt[r] = dot(V[r,:], embed[tgt]) ----------
__global__ void logit_tgt_kernel(const float* __restrict__ V, const float* __restrict__ embed,
                                 const int* __restrict__ tgt, float* __restrict__ lt,
                                 int E, int Nn, int KN, int LM) {
  int row = blockIdx.x;
  int b = row / Nn;
  int i = (row - b * Nn) / KN;
  int g = tgt[b * LM + i];
  __shared__ float sdata[8];
  float v = V[(size_t)row * E + threadIdx.x] * embed[(size_t)g * E + threadIdx.x];
  float s = block_sum(v, sdata);
  if (threadIdx.x == 0) lt[row] = s;
}

// ---------------- final: cent = lse_kn(lt-lse) - log(KN); out = -mean ------
__global__ void final_kernel(const float* __restrict__ lt, const float* __restrict__ lse,
                             float* __restrict__ out, int LM, int KN) {
  int b = blockIdx.x, i = threadIdx.x;  // blockDim = LM = 64 (one wave)
  int base = (b * LM + i) * KN;
  float m = -INFINITY;
  for (int k = 0; k < KN; k++) m = fmaxf(m, lt[base + k] - lse[base + k]);
  float s = 0.f;
  for (int k = 0; k < KN; k++) s += expf(lt[base + k] - lse[base + k] - m);
  float cent = m + logf(s) - logf((float)KN);
#pragma unroll
  for (int o = 32; o > 0; o >>= 1) cent += __shfl_down(cent, o, 64);
  if (i == 0) out[b] = -cent / LM;
}

// ---------------- host-side gemm dispatcher ----------------
static inline void launch_gemm(hipStream_t st, int transA, int transW,
                               const float* A, int lda, const float* W, int ldw,
                               const float* bias, float* C, int ldc,
                               int M, int N, int K, float alpha, int beta, int relu,
                               int shift, int Lroll) {
  dim3 grid(N / 64, M / 64), block(256);
  if (transA)
    gemm_kernel<1, 0><<<grid, block, 0, st>>>(A, lda, W, ldw, bias, C, ldc, K, alpha, beta, relu, 0, Lroll);
  else if (transW)
    gemm_kernel<0, 1><<<grid, block, 0, st>>>(A, lda, W, ldw, bias, C, ldc, K, alpha, beta, relu, shift, Lroll);
  else
    gemm_kernel<0, 0><<<grid, block, 0, st>>>(A, lda, W, ldw, bias, C, ldc, K, alpha, beta, relu, shift, Lroll);
}

extern "C" void kernel_launch(void* const* d_in, const int* in_sizes, int n_in,
                              void* d_out, int out_size, void* d_ws, size_t ws_size,
                              hipStream_t stream) {
  const int* masked = (const int*)d_in[0];
  const int* unmasked = (const int*)d_in[1];
  const int* mask = (const int*)d_in[2];
  const float* embed = (const float*)d_in[3];
  const float* Wt = (const float*)d_in[4];
  const float* bt = (const float*)d_in[5];
  const float* Wtc = (const float*)d_in[6];
  const float* Wq = (const float*)d_in[7];
  const float* Wd = (const float*)d_in[8];
  const float* Wo = (const float*)d_in[9];
  const float* Wu = (const float*)d_in[10];
  const float* Wem = (const float*)d_in[11];
  const float* Wkc = (const float*)d_in[12];
  const float* bkc = (const float*)d_in[13];

  const int B = out_size;                 // 4
  const int BL = in_sizes[0];             // 2048
  const int L = BL / B;                   // 512
  const int BLM = in_sizes[2];            // 256
  const int LM = BLM / B;                 // 64
  const int E = in_sizes[4] / in_sizes[5];// 256 (D*E*E / D*E)
  const int D = in_sizes[5] / E;          // 6
  const int G = in_sizes[3] / E;          // 32000
  const int K = in_sizes[7] / (D * E * E);// 8
  const int KN = in_sizes[12] / (E * E);  // 4
  const int KE = K * E;                   // 2048
  const int N = LM * KN;                  // 256
  const float inv_sqrt_e = 1.0f / sqrtf((float)E);
  const int nch = G / 64;                 // 500

  // workspace carve (floats)
  float* p = (float*)d_ws;
  float* z = p;      p += (size_t)BL * E;
  float* xsa = p;    p += (size_t)BL * E;
  float* xsad = p;   p += (size_t)BL * E;
  float* t1 = p;     p += (size_t)BL * E;
  float* xid = p;    p += (size_t)BL * E;
  float* qy = p;     p += (size_t)BL * KE;               // q, then y
  float* hbuf = p;   p += (size_t)BL * KE;               // per-batch scores (L*K*L <= BL*KE), then relu(y@Wd.T)
  float* gram = p;   p += (size_t)B * E * E;
  float* xx = p;     p += (size_t)B * N * E;
  float* xx2 = p;    p += (size_t)B * N * E;
  float* vv = p;     p += (size_t)B * N * E;
  float* lptok = p;  p += (size_t)BLM * E;
  float* stM = p;    p += (size_t)B * N * nch;
  float* stS = p;    p += (size_t)B * N * nch;
  float* lse = p;    p += (size_t)B * N;
  float* lt = p;     p += (size_t)B * N;
  int* tgt = (int*)p;

  // z = norm(embed[masked]); xsa = z
  embed_norm_kernel<<<BL, E, 0, stream>>>(masked, embed, z, xsa, E);

  for (int d = 0; d < D; d++) {
    const float* wt = Wt + (size_t)d * E * E;
    const float* wtc = Wtc + (size_t)d * E * E;
    const float* wq = Wq + (size_t)d * KE * E;
    const float* wd = Wd + (size_t)d * KE * KE;
    const float* wo = Wo + (size_t)d * KE * E;
    const float* wu = Wu + (size_t)d * E * E;
    const float* btl = bt + (size_t)d * E;

    // t1 = relu(roll(xsa,+1) @ wt)          roll +1 -> src l-1 -> shift -1
    launch_gemm(stream, 0, 0, xsa, E, wt, E, nullptr, t1, E, BL, E, E, 1.f, 0, 1, -1, L);
    // xsad = t1 @ wtc
    launch_gemm(stream, 0, 0, t1, E, wtc, E, nullptr, xsad, E, BL, E, E, 1.f, 0, 0, 0, L);
    // t1 = relu(roll(xsa,-1) @ wtc^T)       roll -1 -> src l+1 -> shift +1
    launch_gemm(stream, 0, 1, xsa, E, wtc, E, nullptr, t1, E, BL, E, E, 1.f, 0, 1, +1, L);
    // xsad += t1 @ wt^T
    launch_gemm(stream, 0, 1, t1, E, wt, E, nullptr, xsad, E, BL, E, E, 1.f, 1, 0, 0, L);
    // xsad += z @ wu^T + bt
    launch_gemm(stream, 0, 1, z, E, wu, E, btl, xsad, E, BL, E, E, 1.f, 1, 0, 0, L);
    // q = xsa @ wq^T   [BL, KE]
    launch_gemm(stream, 0, 1, xsa, E, wq, E, nullptr, qy, KE, BL, KE, E, 1.f, 0, 0, 0, L);
    // attention per batch (reuse hbuf as [L*K, L])
    for (int b = 0; b < B; b++) {
      const float* qb = qy + (size_t)b * L * KE;   // view (L*K, E)
      const float* xb = xsa + (size_t)b * L * E;
      float* yb = qy + (size_t)b * L * KE;
      // h = (q . xsa^T) / sqrt(E)
      launch_gemm(stream, 0, 1, qb, E, xb, E, nullptr, hbuf, L, L * K, L, E, inv_sqrt_e, 0, 0, 0, L);
      softmax_kernel<<<L * K, 256, 0, stream>>>(hbuf, L);
      // y = P @ xsa   (overwrites q for this batch)
      launch_gemm(stream, 0, 0, hbuf, L, xb, E, nullptr, yb, E, L * K, E, L, 1.f, 0, 0, 0, L);
    }
    // hbuf = relu(y @ wd^T)   [BL, KE]
    launch_gemm(stream, 0, 1, qy, KE, wd, KE, nullptr, hbuf, KE, BL, KE, KE, 1.f, 0, 1, 0, L);
    // xid = hbuf @ wo
    launch_gemm(stream, 0, 0, hbuf, KE, wo, E, nullptr, xid, E, BL, E, KE, 1.f, 0, 0, 0, L);
    // xsad = norm(xsad + xid); xsa = norm(xsa + 0.05*xsad)
    addnorm_kernel<<<BL, E, 0, stream>>>(xsad, xid, xsa, E);
  }

  // ---- head ----
  gather_kernel<<<BLM, E, 0, stream>>>(xsa, mask, unmasked, lptok, tgt, L, LM, E);
  for (int b = 0; b < B; b++) {
    const float* xb = xsa + (size_t)b * L * E;
    launch_gemm(stream, 1, 0, xb, E, xb, E, nullptr, gram + (size_t)b * E * E, E, E, E, L, 1.f, 0, 0, 0, L);
  }
  // xx = lptok @ Wkc^T + bkc   [BLM, KN*E] == rows (B*N, E)
  launch_gemm(stream, 0, 1, lptok, E, Wkc, E, bkc, xx, KN * E, BLM, KN * E, E, 1.f, 0, 0, 0, L);
  // xx2[b] = xx[b] @ gram[b]
  for (int b = 0; b < B; b++)
    launch_gemm(stream, 0, 0, xx + (size_t)b * N * E, E, gram + (size_t)b * E * E, E, nullptr,
                xx2 + (size_t)b * N * E, E, N, E, E, 1.f, 0, 0, 0, L);
  // vv = xx2 @ Wem   [B*N, E]
  launch_gemm(stream, 0, 0, xx2, E, Wem, E, nullptr, vv, E, B * N, E, E, 1.f, 0, 0, 0, L);
  // logit stats over G, then lse
  head_stats_kernel<<<dim3(nch, (B * N) / 64), 256, 0, stream>>>(vv, embed, stM, stS, E, nch);
  lse_reduce_kernel<<<B * N, 256, 0, stream>>>(stM, stS, lse, nch);
  logit_tgt_kernel<<<B * N, E, 0, stream>>>(vv, embed, tgt, lt, E, N, KN, LM);
  final_kernel<<<B, LM, 0, stream>>>(lt, lse, (float*)d_out, LM, KN);
}

// Round 2
// 2140.643 us; speedup vs baseline: 3.7427x; 3.7427x over previous
//
#include <hip/hip_runtime.h>
#include <hip/hip_bf16.h>
#include <math.h>

typedef __bf16 bf16x8 __attribute__((ext_vector_type(8)));
typedef float floatx4 __attribute__((ext_vector_type(4)));

__device__ __forceinline__ short f2b(float f) {
  __hip_bfloat16 h = __float2bfloat16(f);
  return *reinterpret_cast<short*>(&h);
}
__device__ __forceinline__ float b2f(short s) {
  unsigned u = ((unsigned)(unsigned short)s) << 16;
  float f;
  __builtin_memcpy(&f, &u, 4);
  return f;
}

// ---------------- block reduction helpers (blockDim multiple of 64) ----------------
__device__ __forceinline__ float block_sum(float v, float* sdata) {
#pragma unroll
  for (int o = 32; o > 0; o >>= 1) v += __shfl_down(v, o, 64);
  __syncthreads();
  int lane = threadIdx.x & 63, wid = threadIdx.x >> 6;
  if (lane == 0) sdata[wid] = v;
  __syncthreads();
  float s = 0.f;
  int nw = blockDim.x >> 6;
  for (int i = 0; i < nw; i++) s += sdata[i];
  return s;
}

__device__ __forceinline__ float block_max(float v, float* sdata) {
#pragma unroll
  for (int o = 32; o > 0; o >>= 1) v = fmaxf(v, __shfl_down(v, o, 64));
  __syncthreads();
  int lane = threadIdx.x & 63, wid = threadIdx.x >> 6;
  if (lane == 0) sdata[wid] = v;
  __syncthreads();
  float m = -INFINITY;
  int nw = blockDim.x >> 6;
  for (int i = 0; i < nw; i++) m = fmaxf(m, sdata[i]);
  return m;
}

// ---------------- conversion kernels ----------------
__global__ void cvt_kernel(const float* __restrict__ src, short* __restrict__ dst, int n4) {
  int i = blockIdx.x * blockDim.x + threadIdx.x;
  if (i < n4) {
    float4 v = ((const float4*)src)[i];
    short4 o;
    o.x = f2b(v.x); o.y = f2b(v.y); o.z = f2b(v.z); o.w = f2b(v.w);
    ((short4*)dst)[i] = o;
  }
}

// dst[c, r] = src[r, c]  (src [R,C] fp32 row-major -> dst [C,R] bf16), batched via z
__global__ void cvtT_kernel(const float* __restrict__ src, short* __restrict__ dst,
                            int R, int C, long sSrc, long sDst) {
  src += (size_t)blockIdx.z * sSrc;
  dst += (size_t)blockIdx.z * sDst;
  __shared__ float tile[32][33];
  int r0 = blockIdx.y * 32, c0 = blockIdx.x * 32;
  int tx = threadIdx.x, ty = threadIdx.y;  // 32 x 8
#pragma unroll
  for (int i = 0; i < 32; i += 8)
    tile[ty + i][tx] = src[(size_t)(r0 + ty + i) * C + c0 + tx];
  __syncthreads();
#pragma unroll
  for (int i = 0; i < 32; i += 8)
    dst[(size_t)(c0 + ty + i) * R + r0 + tx] = f2b(tile[tx][ty + i]);
}

// ---------------- z = norm(embed[masked]); xsa = z (fp32 + bf16 copies) ----------------
__global__ void embed_norm_kernel(const int* __restrict__ masked,
                                  const float* __restrict__ embed,
                                  float* __restrict__ z, float* __restrict__ xsa,
                                  short* __restrict__ z_bf, short* __restrict__ xsa_bf, int E) {
  int row = blockIdx.x;
  int g = masked[row];
  __shared__ float sdata[8];
  float x = embed[(size_t)g * E + threadIdx.x];
  float mean = block_sum(x, sdata) / E;
  float d = x - mean;
  float var = block_sum(d * d, sdata) / (E - 1);
  float val = x / (1.0f + sqrtf(var));
  size_t off = (size_t)row * E + threadIdx.x;
  z[off] = val;
  xsa[off] = val;
  short b = f2b(val);
  z_bf[off] = b;
  xsa_bf[off] = b;
}

// ---------------- bf16 MFMA GEMM (NT): C[m,n] = alpha*sum_k A[m,k]*B[n,k] ----------------
// 128x128 tile, BK=64, 256 threads (4 waves, each 64x64), 16x16x32 MFMA.
// A row remap for jnp.roll via shift/Lroll. Optional bias[n], beta (fp32 C += ),
// relu, bf16 or fp32 output. Batched via blockIdx.z strides.
template <int OUT_BF16>
__global__ __launch_bounds__(256) void bgemm_kernel(
    const short* __restrict__ A, int lda, long sA,
    const short* __restrict__ B, int ldb, long sB,
    void* __restrict__ Cv, int ldc, long sC,
    int Ksz, float alpha, const float* __restrict__ bias,
    int beta, int relu, int shift, int Lroll) {
  A += (size_t)blockIdx.z * sA;
  B += (size_t)blockIdx.z * sB;
  float* Cf = (float*)Cv + (size_t)blockIdx.z * sC;
  short* Cb = (short*)Cv + (size_t)blockIdx.z * sC;
  int m0 = blockIdx.y * 128, n0 = blockIdx.x * 128;
  __shared__ short As[128 * 72];
  __shared__ short Bs[128 * 72];
  int tid = threadIdx.x, lane = tid & 63, w = tid >> 6;
  int wm = (w & 1) * 64, wn = (w >> 1) * 64;
  int ml = lane & 15, q4 = lane >> 4;
  floatx4 acc[4][4] = {};
  for (int k0 = 0; k0 < Ksz; k0 += 64) {
    __syncthreads();
#pragma unroll
    for (int i = 0; i < 4; i++) {
      int q = tid + i * 256;
      int m = q >> 3, c = q & 7;
      int mg = m0 + m;
      if (shift != 0) {
        int bb = mg / Lroll, l = mg - bb * Lroll;
        l = (l + shift + Lroll) % Lroll;
        mg = bb * Lroll + l;
      }
      *(int4*)&As[m * 72 + c * 8] = *(const int4*)(A + (size_t)mg * lda + k0 + c * 8);
      *(int4*)&Bs[m * 72 + c * 8] = *(const int4*)(B + (size_t)(n0 + m) * ldb + k0 + c * 8);
    }
    __syncthreads();
#pragma unroll
    for (int kk = 0; kk < 2; kk++) {
      int koff = kk * 32 + q4 * 8;
      bf16x8 af[4], bfr[4];
#pragma unroll
      for (int mt = 0; mt < 4; mt++)
        af[mt] = *reinterpret_cast<const bf16x8*>(&As[(wm + mt * 16 + ml) * 72 + koff]);
#pragma unroll
      for (int nt = 0; nt < 4; nt++)
        bfr[nt] = *reinterpret_cast<const bf16x8*>(&Bs[(wn + nt * 16 + ml) * 72 + koff]);
#pragma unroll
      for (int mt = 0; mt < 4; mt++)
#pragma unroll
        for (int nt = 0; nt < 4; nt++)
          acc[mt][nt] = __builtin_amdgcn_mfma_f32_16x16x32_bf16(af[mt], bfr[nt], acc[mt][nt], 0, 0, 0);
    }
  }
#pragma unroll
  for (int mt = 0; mt < 4; mt++)
#pragma unroll
    for (int nt = 0; nt < 4; nt++) {
      floatx4 v = acc[mt][nt];
#pragma unroll
      for (int r = 0; r < 4; r++) {
        int grow = m0 + wm + mt * 16 + q4 * 4 + r;
        int gcol = n0 + wn + nt * 16 + ml;
        float x = alpha * v[r];
        if (bias) x += bias[gcol];
        if (beta) x += Cf[(size_t)grow * ldc + gcol];
        if (relu) x = fmaxf(x, 0.f);
        if (OUT_BF16)
          Cb[(size_t)grow * ldc + gcol] = f2b(x);
        else
          Cf[(size_t)grow * ldc + gcol] = x;
      }
    }
}

// ---------------- in-place bf16 row softmax: rows of 512, blockDim 256 ----------------
__global__ void softmax_bf_kernel(short* __restrict__ h) {
  size_t base = (size_t)blockIdx.x * 512;
  int t = threadIdx.x;
  __shared__ float sdata[8];
  float a = b2f(h[base + t]), b = b2f(h[base + t + 256]);
  float m = block_max(fmaxf(a, b), sdata);
  float ea = expf(a - m), eb = expf(b - m);
  float s = block_sum(ea + eb, sdata);
  float inv = 1.f / s;
  h[base + t] = f2b(ea * inv);
  h[base + t + 256] = f2b(eb * inv);
}

// ---------------- xsad=norm(xsad+xid); xsa=norm(xsa+0.05*xsad), write bf16 too ---------
__global__ void addnorm_kernel(const float* __restrict__ xsad,
                               const float* __restrict__ xid,
                               float* __restrict__ xsa, short* __restrict__ xsa_bf, int E) {
  int row = blockIdx.x, t = threadIdx.x;
  __shared__ float sdata[8];
  size_t off = (size_t)row * E + t;
  float s1 = xsad[off] + xid[off];
  float mean = block_sum(s1, sdata) / E;
  float d = s1 - mean;
  float var = block_sum(d * d, sdata) / (E - 1);
  float n1 = s1 / (1.f + sqrtf(var));
  float t2 = xsa[off] + 0.05f * n1;
  float mean2 = block_sum(t2, sdata) / E;
  float d2 = t2 - mean2;
  float var2 = block_sum(d2 * d2, sdata) / (E - 1);
  float res = t2 / (1.f + sqrtf(var2));
  xsa[off] = res;
  xsa_bf[off] = f2b(res);
}

// ---------------- gather masked positions (bf16) + targets ----------------
__global__ void gather_kernel(const float* __restrict__ xsa, const int* __restrict__ mask,
                              const int* __restrict__ unmasked,
                              short* __restrict__ lptok_bf, int* __restrict__ tgt,
                              int L, int LM, int E) {
  int bi = blockIdx.x;
  int b = bi / LM;
  int pos = mask[bi];
  float v = xsa[((size_t)b * L + pos) * E + threadIdx.x];
  lptok_bf[(size_t)bi * E + threadIdx.x] = f2b(v);
  if (threadIdx.x == 0) tgt[bi] = unmasked[b * L + pos];
}

// ---------------- head: MFMA logits + per-(row,128-chunk) max/sumexp stats -------------
__global__ __launch_bounds__(256) void head_stats_kernel(
    const short* __restrict__ V, const short* __restrict__ Eb,
    float* __restrict__ stM, float* __restrict__ stS, int Ksz, int nch) {
  int m0 = blockIdx.y * 128, n0 = blockIdx.x * 128;
  __shared__ short As[128 * 72];
  __shared__ short Bs[128 * 72];
  __shared__ float sred[128][2];
  __shared__ float sred2[128][2];
  int tid = threadIdx.x, lane = tid & 63, w = tid >> 6;
  int wm = (w & 1) * 64, wn = (w >> 1) * 64;
  int ml = lane & 15, q4 = lane >> 4;
  floatx4 acc[4][4] = {};
  for (int k0 = 0; k0 < Ksz; k0 += 64) {
    __syncthreads();
#pragma unroll
    for (int i = 0; i < 4; i++) {
      int q = tid + i * 256;
      int m = q >> 3, c = q & 7;
      *(int4*)&As[m * 72 + c * 8] = *(const int4*)(V + (size_t)(m0 + m) * Ksz + k0 + c * 8);
      *(int4*)&Bs[m * 72 + c * 8] = *(const int4*)(Eb + (size_t)(n0 + m) * Ksz + k0 + c * 8);
    }
    __syncthreads();
#pragma unroll
    for (int kk = 0; kk < 2; kk++) {
      int koff = kk * 32 + q4 * 8;
      bf16x8 af[4], bfr[4];
#pragma unroll
      for (int mt = 0; mt < 4; mt++)
        af[mt] = *reinterpret_cast<const bf16x8*>(&As[(wm + mt * 16 + ml) * 72 + koff]);
#pragma unroll
      for (int nt = 0; nt < 4; nt++)
        bfr[nt] = *reinterpret_cast<const bf16x8*>(&Bs[(wn + nt * 16 + ml) * 72 + koff]);
#pragma unroll
      for (int mt = 0; mt < 4; mt++)
#pragma unroll
        for (int nt = 0; nt < 4; nt++)
          acc[mt][nt] = __builtin_amdgcn_mfma_f32_16x16x32_bf16(af[mt], bfr[nt], acc[mt][nt], 0, 0, 0);
    }
  }
  // per-row max over this 128-col chunk
  float mx[4][4];
#pragma unroll
  for (int mt = 0; mt < 4; mt++)
#pragma unroll
    for (int r = 0; r < 4; r++) {
      float m = fmaxf(fmaxf(acc[mt][0][r], acc[mt][1][r]), fmaxf(acc[mt][2][r], acc[mt][3][r]));
      mx[mt][r] = m;
    }
#pragma unroll
  for (int off = 1; off < 16; off <<= 1)
#pragma unroll
    for (int mt = 0; mt < 4; mt++)
#pragma unroll
      for (int r = 0; r < 4; r++) mx[mt][r] = fmaxf(mx[mt][r], __shfl_xor(mx[mt][r], off, 64));
  if (ml == 0) {
#pragma unroll
    for (int mt = 0; mt < 4; mt++)
#pragma unroll
      for (int r = 0; r < 4; r++) sred[wm + mt * 16 + q4 * 4 + r][w >> 1] = mx[mt][r];
  }
  __syncthreads();
  float sm[4][4];
#pragma unroll
  for (int mt = 0; mt < 4; mt++)
#pragma unroll
    for (int r = 0; r < 4; r++) {
      int row = wm + mt * 16 + q4 * 4 + r;
      float fm = fmaxf(sred[row][0], sred[row][1]);
      float s = 0.f;
#pragma unroll
      for (int nt = 0; nt < 4; nt++) s += expf(acc[mt][nt][r] - fm);
      sm[mt][r] = s;
    }
#pragma unroll
  for (int off = 1; off < 16; off <<= 1)
#pragma unroll
    for (int mt = 0; mt < 4; mt++)
#pragma unroll
      for (int r = 0; r < 4; r++) sm[mt][r] += __shfl_xor(sm[mt][r], off, 64);
  if (ml == 0) {
#pragma unroll
    for (int mt = 0; mt < 4; mt++)
#pragma unroll
      for (int r = 0; r < 4; r++) sred2[wm + mt * 16 + q4 * 4 + r][w >> 1] = sm[mt][r];
  }
  __syncthreads();
  if (tid < 128) {
    int row = tid;
    float fm = fmaxf(sred[row][0], sred[row][1]);
    stM[(size_t)(m0 + row) * nch + blockIdx.x] = fm;
    stS[(size_t)(m0 + row) * nch + blockIdx.x] = sred2[row][0] + sred2[row][1];
  }
}

// ---------------- combine chunk stats -> lse per row ----------------
__global__ void lse_reduce_kernel(const float* __restrict__ statsM,
                                  const float* __restrict__ statsS,
                                  float* __restrict__ lse, int nch) {
  int row = blockIdx.x, t = threadIdx.x;
  float m = -INFINITY, s = 0.f;
  for (int c = t; c < nch; c += blockDim.x) {
    float cm = statsM[(size_t)row * nch + c];
    float cs = statsS[(size_t)row * nch + c];
    float M = fmaxf(m, cm);
    s = s * expf(m - M) + cs * expf(cm - M);
    m = M;
  }
  __shared__ float sm[256], ss[256];
  sm[t] = m;
  ss[t] = s;
  __syncthreads();
  for (int o = 128; o > 0; o >>= 1) {
    if (t < o) {
      float m2 = sm[t + o], s2 = ss[t + o];
      float M = fmaxf(sm[t], m2);
      float sc = ss[t] * expf(sm[t] - M) + s2 * expf(m2 - M);
      sm[t] = M;
      ss[t] = sc;
    }
    __syncthreads();
  }
  if (t == 0) lse[row] = sm[0] + logf(ss[0]);
}

// ---------------- logit at target (bf16 inputs, fp32 dot) ----------------
__global__ void logit_tgt_kernel(const short* __restrict__ V, const short* __restrict__ Eb,
                                 const int* __restrict__ tgt, float* __restrict__ lt,
                                 int E, int Nn, int KN, int LM) {
  int row = blockIdx.x;
  int b = row / Nn;
  int i = (row - b * Nn) / KN;
  int g = tgt[b * LM + i];
  __shared__ float sdata[8];
  float v = b2f(V[(size_t)row * E + threadIdx.x]) * b2f(Eb[(size_t)g * E + threadIdx.x]);
  float s = block_sum(v, sdata);
  if (threadIdx.x == 0) lt[row] = s;
}

// ---------------- final: cent = lse_kn(lt-lse) - log(KN); out = -mean ------
__global__ void final_kernel(const float* __restrict__ lt, const float* __restrict__ lse,
                             float* __restrict__ out, int LM, int KN) {
  int b = blockIdx.x, i = threadIdx.x;  // blockDim = LM = 64 (one wave)
  int base = (b * LM + i) * KN;
  float m = -INFINITY;
  for (int k = 0; k < KN; k++) m = fmaxf(m, lt[base + k] - lse[base + k]);
  float s = 0.f;
  for (int k = 0; k < KN; k++) s += expf(lt[base + k] - lse[base + k] - m);
  float cent = m + logf(s) - logf((float)KN);
#pragma unroll
  for (int o = 32; o > 0; o >>= 1) cent += __shfl_down(cent, o, 64);
  if (i == 0) out[b] = -cent / LM;
}

// ---------------- host-side dispatchers ----------------
static inline void bgemm(hipStream_t st, const short* A, int lda, long sA,
                         const short* B, int ldb, long sB,
                         void* C, int ldc, long sC, int M, int N, int Ksz, int nb,
                         float alpha, const float* bias, int beta, int relu,
                         int out_bf16, int shift, int Lroll) {
  dim3 grid(N / 128, M / 128, nb), block(256);
  if (out_bf16)
    bgemm_kernel<1><<<grid, block, 0, st>>>(A, lda, sA, B, ldb, sB, C, ldc, sC, Ksz, alpha, bias, beta, relu, shift, Lroll);
  else
    bgemm_kernel<0><<<grid, block, 0, st>>>(A, lda, sA, B, ldb, sB, C, ldc, sC, Ksz, alpha, bias, beta, relu, shift, Lroll);
}

static inline void cvt(hipStream_t st, const float* src, short* dst, long n) {
  int n4 = (int)(n / 4);
  cvt_kernel<<<(n4 + 255) / 256, 256, 0, st>>>(src, dst, n4);
}

static inline void cvtT(hipStream_t st, const float* src, short* dst, int R, int C,
                        long sSrc, long sDst, int nb) {
  dim3 grid(C / 32, R / 32, nb), block(32, 8);
  cvtT_kernel<<<grid, block, 0, st>>>(src, dst, R, C, sSrc, sDst);
}

extern "C" void kernel_launch(void* const* d_in, const int* in_sizes, int n_in,
                              void* d_out, int out_size, void* d_ws, size_t ws_size,
                              hipStream_t stream) {
  const int* masked = (const int*)d_in[0];
  const int* unmasked = (const int*)d_in[1];
  const int* mask = (const int*)d_in[2];
  const float* embed = (const float*)d_in[3];
  const float* Wt = (const float*)d_in[4];
  const float* bt = (const float*)d_in[5];
  const float* Wtc = (const float*)d_in[6];
  const float* Wq = (const float*)d_in[7];
  const float* Wd = (const float*)d_in[8];
  const float* Wo = (const float*)d_in[9];
  const float* Wu = (const float*)d_in[10];
  const float* Wem = (const float*)d_in[11];
  const float* Wkc = (const float*)d_in[12];
  const float* bkc = (const float*)d_in[13];

  const int B = out_size;                  // 4
  const int BL = in_sizes[0];              // 2048
  const int L = BL / B;                    // 512
  const int BLM = in_sizes[2];             // 256
  const int LM = BLM / B;                  // 64
  const int E = in_sizes[4] / in_sizes[5]; // 256
  const int D = in_sizes[5] / E;           // 6
  const int G = in_sizes[3] / E;           // 32000
  const int K = in_sizes[7] / (D * E * E); // 8
  const int KN = in_sizes[12] / (E * E);   // 4
  const int KE = K * E;                    // 2048
  const int N = LM * KN;                   // 256
  const float inv_sqrt_e = 1.0f / sqrtf((float)E);
  const int nch = G / 128;                 // 250

  // ---- workspace carve (256B aligned) ----
  char* base = (char*)d_ws;
  size_t off = 0;
  auto carve = [&](size_t bytes) {
    char* p = base + off;
    off += (bytes + 255) & ~(size_t)255;
    return p;
  };
  float* z = (float*)carve((size_t)BL * E * 4);
  float* xsa = (float*)carve((size_t)BL * E * 4);
  float* xsad = (float*)carve((size_t)BL * E * 4);
  float* xid = (float*)carve((size_t)BL * E * 4);
  float* stM = (float*)carve((size_t)B * N * nch * 4);
  float* stS = (float*)carve((size_t)B * N * nch * 4);
  float* lse = (float*)carve((size_t)B * N * 4);
  float* lt = (float*)carve((size_t)B * N * 4);
  int* tgt = (int*)carve((size_t)B * LM * 4);
  short* z_bf = (short*)carve((size_t)BL * E * 2);
  short* xsa_bf = (short*)carve((size_t)BL * E * 2);
  short* xsaT_bf = (short*)carve((size_t)B * E * L * 2);
  short* t1_bf = (short*)carve((size_t)BL * E * 2);
  short* qy_bf = (short*)carve((size_t)BL * KE * 2);
  short* hP_bf = (short*)carve((size_t)B * L * K * L * 2);  // scores/probs; later r=relu(y@WdT)
  short* r_bf = hP_bf;                                      // alias (after attention done)
  short* wd_bf = (short*)carve((size_t)KE * KE * 2);
  short* wq_bf = (short*)carve((size_t)KE * E * 2);
  short* woT_bf = (short*)carve((size_t)E * KE * 2);
  short* wtA_bf = (short*)carve((size_t)D * E * E * 2);
  short* wtTA_bf = (short*)carve((size_t)D * E * E * 2);
  short* wtcA_bf = (short*)carve((size_t)D * E * E * 2);
  short* wtcTA_bf = (short*)carve((size_t)D * E * E * 2);
  short* wuA_bf = (short*)carve((size_t)D * E * E * 2);
  short* embed_bf = (short*)carve((size_t)G * E * 2);
  short* WemT_bf = (short*)carve((size_t)E * E * 2);
  short* Wkc_bf = (short*)carve((size_t)KN * E * E * 2);
  short* gram_bf = (short*)carve((size_t)B * E * E * 2);
  short* xx_bf = (short*)carve((size_t)B * N * E * 2);
  short* xx2_bf = (short*)carve((size_t)B * N * E * 2);
  short* vv_bf = (short*)carve((size_t)B * N * E * 2);
  short* lptok_bf = (short*)carve((size_t)BLM * E * 2);

  // ---- up-front conversions ----
  cvt(stream, embed, embed_bf, (long)G * E);
  cvt(stream, Wkc, Wkc_bf, (long)KN * E * E);
  cvtT(stream, Wem, WemT_bf, E, E, 0, 0, 1);
  cvt(stream, Wt, wtA_bf, (long)D * E * E);
  cvt(stream, Wtc, wtcA_bf, (long)D * E * E);
  cvt(stream, Wu, wuA_bf, (long)D * E * E);
  cvtT(stream, Wt, wtTA_bf, E, E, (long)E * E, (long)E * E, D);
  cvtT(stream, Wtc, wtcTA_bf, E, E, (long)E * E, (long)E * E, D);

  // z = norm(embed[masked]); xsa = z
  embed_norm_kernel<<<BL, E, 0, stream>>>(masked, embed, z, xsa, z_bf, xsa_bf, E);
  cvtT(stream, xsa, xsaT_bf, L, E, (long)L * E, (long)E * L, B);

  for (int d = 0; d < D; d++) {
    const short* wt = wtA_bf + (size_t)d * E * E;
    const short* wtT = wtTA_bf + (size_t)d * E * E;
    const short* wtc = wtcA_bf + (size_t)d * E * E;
    const short* wtcT = wtcTA_bf + (size_t)d * E * E;
    const short* wu = wuA_bf + (size_t)d * E * E;
    const float* btl = bt + (size_t)d * E;

    cvt(stream, Wd + (size_t)d * KE * KE, wd_bf, (long)KE * KE);
    cvt(stream, Wq + (size_t)d * KE * E, wq_bf, (long)KE * E);
    cvtT(stream, Wo + (size_t)d * KE * E, woT_bf, KE, E, 0, 0, 1);

    // t1 = relu(roll(xsa,+1) @ wt)   (NT: B = wt^T)
    bgemm(stream, xsa_bf, E, 0, wtT, E, 0, t1_bf, E, 0, BL, E, E, 1, 1.f, nullptr, 0, 1, 1, -1, L);
    // xsad = t1 @ wtc                (fp32 out)
    bgemm(stream, t1_bf, E, 0, wtcT, E, 0, xsad, E, 0, BL, E, E, 1, 1.f, nullptr, 0, 0, 0, 0, L);
    // t1 = relu(roll(xsa,-1) @ wtc^T)
    bgemm(stream, xsa_bf, E, 0, wtc, E, 0, t1_bf, E, 0, BL, E, E, 1, 1.f, nullptr, 0, 1, 1, +1, L);
    // xsad += t1 @ wt^T
    bgemm(stream, t1_bf, E, 0, wt, E, 0, xsad, E, 0, BL, E, E, 1, 1.f, nullptr, 1, 0, 0, 0, L);
    // xsad += z @ wu^T + bt
    bgemm(stream, z_bf, E, 0, wu, E, 0, xsad, E, 0, BL, E, E, 1, 1.f, btl, 1, 0, 0, 0, L);
    // q = xsa @ wq^T   [BL, KE] bf16
    bgemm(stream, xsa_bf, E, 0, wq_bf, E, 0, qy_bf, KE, 0, BL, KE, E, 1, 1.f, nullptr, 0, 0, 1, 0, L);
    // h = q . xsa^T / sqrt(E)   batched over B: [L*K, L] bf16
    bgemm(stream, qy_bf, E, (long)L * KE, xsa_bf, E, (long)L * E,
          hP_bf, L, (long)L * K * L, L * K, L, E, B, inv_sqrt_e, nullptr, 0, 0, 1, 0, L);
    // softmax rows (in-place bf16)
    softmax_bf_kernel<<<B * L * K, 256, 0, stream>>>(hP_bf);
    // y = P @ xsa  -> overwrite q buffer, batched
    bgemm(stream, hP_bf, L, (long)L * K * L, xsaT_bf, L, (long)E * L,
          qy_bf, E, (long)L * KE, L * K, E, L, B, 1.f, nullptr, 0, 0, 1, 0, L);
    // r = relu(y @ wd^T)  [BL, KE] bf16 (aliases hP)
    bgemm(stream, qy_bf, KE, 0, wd_bf, KE, 0, r_bf, KE, 0, BL, KE, KE, 1, 1.f, nullptr, 0, 1, 1, 0, L);
    // xid = r @ wo   (fp32 out)
    bgemm(stream, r_bf, KE, 0, woT_bf, KE, 0, xid, E, 0, BL, E, KE, 1, 1.f, nullptr, 0, 0, 0, 0, L);
    // xsad = norm(xsad + xid); xsa = norm(xsa + 0.05*xsad)
    addnorm_kernel<<<BL, E, 0, stream>>>(xsad, xid, xsa, xsa_bf, E);
    cvtT(stream, xsa, xsaT_bf, L, E, (long)L * E, (long)E * L, B);
  }

  // ---- head ----
  gather_kernel<<<BLM, E, 0, stream>>>(xsa, mask, unmasked, lptok_bf, tgt, L, LM, E);
  // gram[b] = xsa^T @ xsa   (NT with A=B=xsaT) -> bf16
  bgemm(stream, xsaT_bf, L, (long)E * L, xsaT_bf, L, (long)E * L,
        gram_bf, E, (long)E * E, E, E, L, B, 1.f, nullptr, 0, 0, 1, 0, L);
  // xx = lptok @ Wkc^T + bkc   [BLM, KN*E] -> viewed [B*N, E] bf16
  bgemm(stream, lptok_bf, E, 0, Wkc_bf, E, 0, xx_bf, KN * E, 0, BLM, KN * E, E, 1, 1.f, bkc, 0, 0, 1, 0, L);
  // xx2[b] = xx[b] @ gram[b]  (gram symmetric -> NT with B=gram)
  bgemm(stream, xx_bf, E, (long)N * E, gram_bf, E, (long)E * E,
        xx2_bf, E, (long)N * E, N, E, E, B, 1.f, nullptr, 0, 0, 1, 0, L);
  // vv = xx2 @ Wem   [B*N, E] bf16
  bgemm(stream, xx2_bf, E, 0, WemT_bf, E, 0, vv_bf, E, 0, B * N, E, E, 1, 1.f, nullptr, 0, 0, 1, 0, L);
  // logits stats over G, then lse
  head_stats_kernel<<<dim3(nch, (B * N) / 128), 256, 0, stream>>>(vv_bf, embed_bf, stM, stS, E, nch);
  lse_reduce_kernel<<<B * N, 256, 0, stream>>>(stM, stS, lse, nch);
  logit_tgt_kernel<<<B * N, E, 0, stream>>>(vv_bf, embed_bf, tgt, lt, E, N, KN, LM);
  final_kernel<<<B, LM, 0, stream>>>(lt, lse, (float*)d_out, LM, KN);
}

// Round 4
// 1263.880 us; speedup vs baseline: 6.3391x; 1.6937x over previous
//
#include <hip/hip_runtime.h>
#include <hip/hip_bf16.h>
#include <math.h>

typedef __bf16 bf16x8 __attribute__((ext_vector_type(8)));
typedef float floatx4 __attribute__((ext_vector_type(4)));

__device__ __forceinline__ short f2b(float f) {
  __hip_bfloat16 h = __float2bfloat16(f);
  return *reinterpret_cast<short*>(&h);
}
__device__ __forceinline__ float b2f(short s) {
  unsigned u = ((unsigned)(unsigned short)s) << 16;
  float f;
  __builtin_memcpy(&f, &u, 4);
  return f;
}

// async global->LDS, 16B per lane; lds base must be wave-uniform
__device__ __forceinline__ void gl2lds16(const void* g, void* l) {
  __builtin_amdgcn_global_load_lds((__attribute__((address_space(1))) const void*)g,
                                   (__attribute__((address_space(3))) void*)l, 16, 0, 0);
}

// ---------------- block reduction helpers ----------------
__device__ __forceinline__ float block_sum(float v, float* sdata) {
#pragma unroll
  for (int o = 32; o > 0; o >>= 1) v += __shfl_down(v, o, 64);
  __syncthreads();
  int lane = threadIdx.x & 63, wid = threadIdx.x >> 6;
  if (lane == 0) sdata[wid] = v;
  __syncthreads();
  float s = 0.f;
  int nw = blockDim.x >> 6;
  for (int i = 0; i < nw; i++) s += sdata[i];
  return s;
}

// ---------------- conversion kernels ----------------
__global__ void cvt_kernel(const float* __restrict__ src, short* __restrict__ dst, int n4) {
  int i = blockIdx.x * blockDim.x + threadIdx.x;
  if (i < n4) {
    float4 v = ((const float4*)src)[i];
    short4 o;
    o.x = f2b(v.x); o.y = f2b(v.y); o.z = f2b(v.z); o.w = f2b(v.w);
    ((short4*)dst)[i] = o;
  }
}

// dst[r*ldD + c] = bf16(src[r*ldS + c]); grid (C/32, R/32, nb), block (32,8)
__global__ void cvt2_kernel(const float* __restrict__ src, short* __restrict__ dst,
                            int ldS, int ldD, long sS, long sD) {
  src += (size_t)blockIdx.z * sS;
  dst += (size_t)blockIdx.z * sD;
  int c = blockIdx.x * 32 + threadIdx.x;
  int r0 = blockIdx.y * 32 + threadIdx.y;
#pragma unroll
  for (int i = 0; i < 32; i += 8)
    dst[(size_t)(r0 + i) * ldD + c] = f2b(src[(size_t)(r0 + i) * ldS + c]);
}

// dst[c*ldD + r] = bf16(src[r*ldS + c]); grid (C/32, R/32, nb), block (32,8)
__global__ void cvtT2_kernel(const float* __restrict__ src, short* __restrict__ dst,
                             int ldS, int ldD, long sS, long sD) {
  src += (size_t)blockIdx.z * sS;
  dst += (size_t)blockIdx.z * sD;
  __shared__ float tile[32][33];
  int r0 = blockIdx.y * 32, c0 = blockIdx.x * 32;
  int tx = threadIdx.x, ty = threadIdx.y;
#pragma unroll
  for (int i = 0; i < 32; i += 8)
    tile[ty + i][tx] = src[(size_t)(r0 + ty + i) * ldS + c0 + tx];
  __syncthreads();
#pragma unroll
  for (int i = 0; i < 32; i += 8)
    dst[(size_t)(c0 + ty + i) * ldD + r0 + tx] = f2b(tile[tx][ty + i]);
}

// ---------------- embed gather + norm; also fills z-slot of t3 ----------------
__global__ void embed_norm_kernel(const int* __restrict__ masked,
                                  const float* __restrict__ embed,
                                  float* __restrict__ xsa, short* __restrict__ xsa_bf,
                                  short* __restrict__ t3, int E) {
  int row = blockIdx.x;
  int g = masked[row];
  __shared__ float sdata[8];
  float x = embed[(size_t)g * E + threadIdx.x];
  float mean = block_sum(x, sdata) / E;
  float d = x - mean;
  float var = block_sum(d * d, sdata) / (E - 1);
  float val = x / (1.0f + sqrtf(var));
  size_t off = (size_t)row * E + threadIdx.x;
  xsa[off] = val;
  short b = f2b(val);
  xsa_bf[off] = b;
  t3[(size_t)row * 3 * E + 2 * E + threadIdx.x] = b;
}

// ---------------- bf16 MFMA GEMM (NT), async dbuf, XOR swizzle ----------------
// C[m,n] = alpha*sum_k A[m,k]*B[n,k] [+bias[n]] [relu]; 128x128 tile, BK=64.
// A-row roll: shift = (n0 < nsplit ? shiftA : shiftB) applied per-batch of Lroll rows.
template <int OUT_BF16>
__global__ __launch_bounds__(256) void bgemm_kernel(
    const short* __restrict__ A, int lda, long sA,
    const short* __restrict__ B, int ldb, long sB,
    void* __restrict__ Cv, int ldc, long sC,
    int Ksz, float alpha, const float* __restrict__ bias,
    int relu, int shiftA, int shiftB, int nsplit, int Lroll) {
  A += (size_t)blockIdx.z * sA;
  B += (size_t)blockIdx.z * sB;
  float* Cf = (float*)Cv + (size_t)blockIdx.z * sC;
  short* Cb = (short*)Cv + (size_t)blockIdx.z * sC;
  int m0 = blockIdx.y * 128, n0 = blockIdx.x * 128;
  int shift = (n0 < nsplit) ? shiftA : shiftB;
  __shared__ short As[2][8192];
  __shared__ short Bs[2][8192];
  int tid = threadIdx.x, lane = tid & 63, w = tid >> 6;
  int wm = (w & 1) * 64, wn = (w >> 1) * 64;
  int ml = lane & 15, q4 = lane >> 4, sw = ml & 7;

  // staging source pointers: chunk id q = i*256 + w*64 + lane
  const short* aSrc[4];
  const short* bSrc[4];
#pragma unroll
  for (int i = 0; i < 4; i++) {
    int q = i * 256 + w * 64 + lane;
    int m = q >> 3, cl = q & 7;
    int cs = cl ^ (m & 7);
    int mg = m0 + m;
    if (shift != 0) {
      int bb = mg / Lroll, l = mg - bb * Lroll;
      l = (l + shift + Lroll) % Lroll;
      mg = bb * Lroll + l;
    }
    aSrc[i] = A + (size_t)mg * lda + cs * 8;
    bSrc[i] = B + (size_t)(n0 + m) * ldb + cs * 8;
  }
  // prologue: stage tile 0
#pragma unroll
  for (int i = 0; i < 4; i++) {
    gl2lds16(aSrc[i], &As[0][(i * 256 + w * 64) * 8]);
    gl2lds16(bSrc[i], &Bs[0][(i * 256 + w * 64) * 8]);
  }
  floatx4 acc[4][4] = {};
  int nT = Ksz >> 6;
  for (int t = 0; t < nT; t++) {
    __syncthreads();  // drains vmcnt: tile t resident; all waves done with t-1
    int cur = t & 1;
    if (t + 1 < nT) {
      int nxt = cur ^ 1, ko = (t + 1) * 64;
#pragma unroll
      for (int i = 0; i < 4; i++) {
        gl2lds16(aSrc[i] + ko, &As[nxt][(i * 256 + w * 64) * 8]);
        gl2lds16(bSrc[i] + ko, &Bs[nxt][(i * 256 + w * 64) * 8]);
      }
    }
#pragma unroll
    for (int kk = 0; kk < 2; kk++) {
      int j = (kk * 4 + q4);
      bf16x8 af[4], bg[4];
#pragma unroll
      for (int mt = 0; mt < 4; mt++) {
        int r = wm + mt * 16 + ml;
        af[mt] = *reinterpret_cast<const bf16x8*>(&As[cur][r * 64 + (j ^ sw) * 8]);
      }
#pragma unroll
      for (int nt = 0; nt < 4; nt++) {
        int r = wn + nt * 16 + ml;
        bg[nt] = *reinterpret_cast<const bf16x8*>(&Bs[cur][r * 64 + (j ^ sw) * 8]);
      }
#pragma unroll
      for (int mt = 0; mt < 4; mt++)
#pragma unroll
        for (int nt = 0; nt < 4; nt++)
          acc[mt][nt] = __builtin_amdgcn_mfma_f32_16x16x32_bf16(af[mt], bg[nt], acc[mt][nt], 0, 0, 0);
    }
  }
#pragma unroll
  for (int mt = 0; mt < 4; mt++)
#pragma unroll
    for (int nt = 0; nt < 4; nt++) {
      floatx4 v = acc[mt][nt];
#pragma unroll
      for (int r = 0; r < 4; r++) {
        int grow = m0 + wm + mt * 16 + q4 * 4 + r;
        int gcol = n0 + wn + nt * 16 + ml;
        float x = alpha * v[r];
        if (bias) x += bias[gcol];
        if (relu) x = fmaxf(x, 0.f);
        if (OUT_BF16)
          Cb[(size_t)grow * ldc + gcol] = f2b(x);
        else
          Cf[(size_t)grow * ldc + gcol] = x;
      }
    }
}

// ---------------- wave-per-row softmax, rows of 512 bf16 ----------------
__global__ void softmax_bf_kernel(short* __restrict__ h) {
  int lane = threadIdx.x & 63;
  size_t row = (size_t)blockIdx.x * 4 + (threadIdx.x >> 6);
  short* p = h + row * 512 + lane * 8;
  int4 raw = *(const int4*)p;
  short sh[8];
  __builtin_memcpy(sh, &raw, 16);
  float v[8];
  float m = -INFINITY;
#pragma unroll
  for (int i = 0; i < 8; i++) {
    v[i] = b2f(sh[i]);
    m = fmaxf(m, v[i]);
  }
#pragma unroll
  for (int o = 1; o < 64; o <<= 1) m = fmaxf(m, __shfl_xor(m, o, 64));
  float s = 0.f;
#pragma unroll
  for (int i = 0; i < 8; i++) {
    v[i] = expf(v[i] - m);
    s += v[i];
  }
#pragma unroll
  for (int o = 1; o < 64; o <<= 1) s += __shfl_xor(s, o, 64);
  float inv = 1.f / s;
#pragma unroll
  for (int i = 0; i < 8; i++) sh[i] = f2b(v[i] * inv);
  __builtin_memcpy(&raw, sh, 16);
  *(int4*)p = raw;
}

// ---------------- xsad=norm(xsad+xid); xsa=norm(xsa+0.05*xsad) ----------------
__global__ void addnorm_kernel(const float* __restrict__ xsad,
                               const float* __restrict__ xid,
                               float* __restrict__ xsa, short* __restrict__ xsa_bf, int E) {
  int row = blockIdx.x, t = threadIdx.x;
  __shared__ float sdata[8];
  size_t off = (size_t)row * E + t;
  float s1 = xsad[off] + xid[off];
  float mean = block_sum(s1, sdata) / E;
  float d = s1 - mean;
  float var = block_sum(d * d, sdata) / (E - 1);
  float n1 = s1 / (1.f + sqrtf(var));
  float t2 = xsa[off] + 0.05f * n1;
  float mean2 = block_sum(t2, sdata) / E;
  float d2 = t2 - mean2;
  float var2 = block_sum(d2 * d2, sdata) / (E - 1);
  float res = t2 / (1.f + sqrtf(var2));
  xsa[off] = res;
  xsa_bf[off] = f2b(res);
}

// ---------------- gather masked positions (bf16) + targets ----------------
__global__ void gather_kernel(const float* __restrict__ xsa, const int* __restrict__ mask,
                              const int* __restrict__ unmasked,
                              short* __restrict__ lptok_bf, int* __restrict__ tgt,
                              int L, int LM, int E) {
  int bi = blockIdx.x;
  int b = bi / LM;
  int pos = mask[bi];
  float v = xsa[((size_t)b * L + pos) * E + threadIdx.x];
  lptok_bf[(size_t)bi * E + threadIdx.x] = f2b(v);
  if (threadIdx.x == 0) tgt[bi] = unmasked[b * L + pos];
}

// ---------------- head: MFMA logits + per-(row,128-chunk) max/sumexp ----------------
__global__ __launch_bounds__(256) void head_stats_kernel(
    const short* __restrict__ V, const short* __restrict__ Eb,
    float* __restrict__ stM, float* __restrict__ stS, int Ksz, int nch) {
  int m0 = blockIdx.y * 128, n0 = blockIdx.x * 128;
  __shared__ short As[2][8192];
  __shared__ short Bs[2][8192];
  int tid = threadIdx.x, lane = tid & 63, w = tid >> 6;
  int wm = (w & 1) * 64, wn = (w >> 1) * 64;
  int ml = lane & 15, q4 = lane >> 4, sw = ml & 7;
  const short* aSrc[4];
  const short* bSrc[4];
#pragma unroll
  for (int i = 0; i < 4; i++) {
    int q = i * 256 + w * 64 + lane;
    int m = q >> 3, cl = q & 7;
    int cs = cl ^ (m & 7);
    aSrc[i] = V + (size_t)(m0 + m) * Ksz + cs * 8;
    bSrc[i] = Eb + (size_t)(n0 + m) * Ksz + cs * 8;
  }
#pragma unroll
  for (int i = 0; i < 4; i++) {
    gl2lds16(aSrc[i], &As[0][(i * 256 + w * 64) * 8]);
    gl2lds16(bSrc[i], &Bs[0][(i * 256 + w * 64) * 8]);
  }
  floatx4 acc[4][4] = {};
  int nT = Ksz >> 6;
  for (int t = 0; t < nT; t++) {
    __syncthreads();
    int cur = t & 1;
    if (t + 1 < nT) {
      int nxt = cur ^ 1, ko = (t + 1) * 64;
#pragma unroll
      for (int i = 0; i < 4; i++) {
        gl2lds16(aSrc[i] + ko, &As[nxt][(i * 256 + w * 64) * 8]);
        gl2lds16(bSrc[i] + ko, &Bs[nxt][(i * 256 + w * 64) * 8]);
      }
    }
#pragma unroll
    for (int kk = 0; kk < 2; kk++) {
      int j = (kk * 4 + q4);
      bf16x8 af[4], bg[4];
#pragma unroll
      for (int mt = 0; mt < 4; mt++) {
        int r = wm + mt * 16 + ml;
        af[mt] = *reinterpret_cast<const bf16x8*>(&As[cur][r * 64 + (j ^ sw) * 8]);
      }
#pragma unroll
      for (int nt = 0; nt < 4; nt++) {
        int r = wn + nt * 16 + ml;
        bg[nt] = *reinterpret_cast<const bf16x8*>(&Bs[cur][r * 64 + (j ^ sw) * 8]);
      }
#pragma unroll
      for (int mt = 0; mt < 4; mt++)
#pragma unroll
        for (int nt = 0; nt < 4; nt++)
          acc[mt][nt] = __builtin_amdgcn_mfma_f32_16x16x32_bf16(af[mt], bg[nt], acc[mt][nt], 0, 0, 0);
    }
  }
  // reuse LDS for stats (all ds_reads done; barrier below protects)
  __syncthreads();
  float (*sred)[2] = (float (*)[2]) & As[0][0];
  float (*sred2)[2] = (float (*)[2]) & Bs[0][0];
  float mx[4][4];
#pragma unroll
  for (int mt = 0; mt < 4; mt++)
#pragma unroll
    for (int r = 0; r < 4; r++)
      mx[mt][r] = fmaxf(fmaxf(acc[mt][0][r], acc[mt][1][r]), fmaxf(acc[mt][2][r], acc[mt][3][r]));
#pragma unroll
  for (int off = 1; off < 16; off <<= 1)
#pragma unroll
    for (int mt = 0; mt < 4; mt++)
#pragma unroll
      for (int r = 0; r < 4; r++) mx[mt][r] = fmaxf(mx[mt][r], __shfl_xor(mx[mt][r], off, 64));
  if (ml == 0)
#pragma unroll
    for (int mt = 0; mt < 4; mt++)
#pragma unroll
      for (int r = 0; r < 4; r++) sred[wm + mt * 16 + q4 * 4 + r][w >> 1] = mx[mt][r];
  __syncthreads();
  float sm[4][4];
#pragma unroll
  for (int mt = 0; mt < 4; mt++)
#pragma unroll
    for (int r = 0; r < 4; r++) {
      int row = wm + mt * 16 + q4 * 4 + r;
      float fm = fmaxf(sred[row][0], sred[row][1]);
      float s = 0.f;
#pragma unroll
      for (int nt = 0; nt < 4; nt++) s += expf(acc[mt][nt][r] - fm);
      sm[mt][r] = s;
    }
#pragma unroll
  for (int off = 1; off < 16; off <<= 1)
#pragma unroll
    for (int mt = 0; mt < 4; mt++)
#pragma unroll
      for (int r = 0; r < 4; r++) sm[mt][r] += __shfl_xor(sm[mt][r], off, 64);
  if (ml == 0)
#pragma unroll
    for (int mt = 0; mt < 4; mt++)
#pragma unroll
      for (int r = 0; r < 4; r++) sred2[wm + mt * 16 + q4 * 4 + r][w >> 1] = sm[mt][r];
  __syncthreads();
  if (tid < 128) {
    float fm = fmaxf(sred[tid][0], sred[tid][1]);
    stM[(size_t)(m0 + tid) * nch + blockIdx.x] = fm;
    stS[(size_t)(m0 + tid) * nch + blockIdx.x] = sred2[tid][0] + sred2[tid][1];
  }
}

// ---------------- combine chunk stats -> lse per row ----------------
__global__ void lse_reduce_kernel(const float* __restrict__ statsM,
                                  const float* __restrict__ statsS,
                                  float* __restrict__ lse, int nch) {
  int row = blockIdx.x, t = threadIdx.x;
  float m = -INFINITY, s = 0.f;
  for (int c = t; c < nch; c += blockDim.x) {
    float cm = statsM[(size_t)row * nch + c];
    float cs = statsS[(size_t)row * nch + c];
    float M = fmaxf(m, cm);
    s = s * expf(m - M) + cs * expf(cm - M);
    m = M;
  }
  __shared__ float sm[256], ss[256];
  sm[t] = m;
  ss[t] = s;
  __syncthreads();
  for (int o = 128; o > 0; o >>= 1) {
    if (t < o) {
      float m2 = sm[t + o], s2 = ss[t + o];
      float M = fmaxf(sm[t], m2);
      float sc = ss[t] * expf(sm[t] - M) + s2 * expf(m2 - M);
      sm[t] = M;
      ss[t] = sc;
    }
    __syncthreads();
  }
  if (t == 0) lse[row] = sm[0] + logf(ss[0]);
}

// ---------------- logit at target ----------------
__global__ void logit_tgt_kernel(const short* __restrict__ V, const short* __restrict__ Eb,
                                 const int* __restrict__ tgt, float* __restrict__ lt,
                                 int E, int Nn, int KN, int LM) {
  int row = blockIdx.x;
  int b = row / Nn;
  int i = (row - b * Nn) / KN;
  int g = tgt[b * LM + i];
  __shared__ float sdata[8];
  float v = b2f(V[(size_t)row * E + threadIdx.x]) * b2f(Eb[(size_t)g * E + threadIdx.x]);
  float s = block_sum(v, sdata);
  if (threadIdx.x == 0) lt[row] = s;
}

// ---------------- final ----------------
__global__ void final_kernel(const float* __restrict__ lt, const float* __restrict__ lse,
                             float* __restrict__ out, int LM, int KN) {
  int b = blockIdx.x, i = threadIdx.x;
  int base = (b * LM + i) * KN;
  float m = -INFINITY;
  for (int k = 0; k < KN; k++) m = fmaxf(m, lt[base + k] - lse[base + k]);
  float s = 0.f;
  for (int k = 0; k < KN; k++) s += expf(lt[base + k] - lse[base + k] - m);
  float cent = m + logf(s) - logf((float)KN);
#pragma unroll
  for (int o = 32; o > 0; o >>= 1) cent += __shfl_down(cent, o, 64);
  if (i == 0) out[b] = -cent / LM;
}

// ---------------- host dispatchers ----------------
static inline void bgemm(hipStream_t st, const short* A, int lda, long sA,
                         const short* B, int ldb, long sB,
                         void* C, int ldc, long sC, int M, int N, int Ksz, int nb,
                         float alpha, const float* bias, int relu, int out_bf16,
                         int shiftA, int shiftB, int nsplit, int Lroll) {
  dim3 grid(N / 128, M / 128, nb), block(256);
  if (out_bf16)
    bgemm_kernel<1><<<grid, block, 0, st>>>(A, lda, sA, B, ldb, sB, C, ldc, sC, Ksz, alpha, bias, relu, shiftA, shiftB, nsplit, Lroll);
  else
    bgemm_kernel<0><<<grid, block, 0, st>>>(A, lda, sA, B, ldb, sB, C, ldc, sC, Ksz, alpha, bias, relu, shiftA, shiftB, nsplit, Lroll);
}

static inline void cvt(hipStream_t st, const float* src, short* dst, long n) {
  int n4 = (int)(n / 4);
  cvt_kernel<<<(n4 + 255) / 256, 256, 0, st>>>(src, dst, n4);
}

static inline void cvt2(hipStream_t st, const float* src, short* dst, int R, int C,
                        int ldS, int ldD, long sS, long sD, int nb) {
  dim3 grid(C / 32, R / 32, nb), block(32, 8);
  cvt2_kernel<<<grid, block, 0, st>>>(src, dst, ldS, ldD, sS, sD);
}

static inline void cvtT2(hipStream_t st, const float* src, short* dst, int R, int C,
                         int ldS, int ldD, long sS, long sD, int nb) {
  dim3 grid(C / 32, R / 32, nb), block(32, 8);
  cvtT2_kernel<<<grid, block, 0, st>>>(src, dst, ldS, ldD, sS, sD);
}

extern "C" void kernel_launch(void* const* d_in, const int* in_sizes, int n_in,
                              void* d_out, int out_size, void* d_ws, size_t ws_size,
                              hipStream_t stream) {
  const int* masked = (const int*)d_in[0];
  const int* unmasked = (const int*)d_in[1];
  const int* mask = (const int*)d_in[2];
  const float* embed = (const float*)d_in[3];
  const float* Wt = (const float*)d_in[4];
  const float* bt = (const float*)d_in[5];
  const float* Wtc = (const float*)d_in[6];
  const float* Wq = (const float*)d_in[7];
  const float* Wd = (const float*)d_in[8];
  const float* Wo = (const float*)d_in[9];
  const float* Wu = (const float*)d_in[10];
  const float* Wem = (const float*)d_in[11];
  const float* Wkc = (const float*)d_in[12];
  const float* bkc = (const float*)d_in[13];

  const int B = out_size;                  // 4
  const int BL = in_sizes[0];              // 2048
  const int L = BL / B;                    // 512
  const int BLM = in_sizes[2];             // 256
  const int LM = BLM / B;                  // 64
  const int E = in_sizes[4] / in_sizes[5]; // 256
  const int D = in_sizes[5] / E;           // 6
  const int G = in_sizes[3] / E;           // 32000
  const int K = in_sizes[7] / (D * E * E); // 8
  const int KN = in_sizes[12] / (E * E);   // 4
  const int KE = K * E;                    // 2048
  const int N = LM * KN;                   // 256
  const float inv_sqrt_e = 1.0f / sqrtf((float)E);
  const int nch = G / 128;                 // 250
  const int E3 = 3 * E;                    // 768

  // ---- workspace carve ----
  char* base = (char*)d_ws;
  size_t off = 0;
  auto carve = [&](size_t bytes) {
    char* p = base + off;
    off += (bytes + 255) & ~(size_t)255;
    return p;
  };
  float* xsa = (float*)carve((size_t)BL * E * 4);
  float* xsad = (float*)carve((size_t)BL * E * 4);
  float* xid = (float*)carve((size_t)BL * E * 4);
  float* stM = (float*)carve((size_t)B * N * nch * 4);
  float* stS = (float*)carve((size_t)B * N * nch * 4);
  float* lse = (float*)carve((size_t)B * N * 4);
  float* lt = (float*)carve((size_t)B * N * 4);
  int* tgt = (int*)carve((size_t)B * LM * 4);
  short* xsa_bf = (short*)carve((size_t)BL * E * 2);
  short* xsaT_bf = (short*)carve((size_t)B * E * L * 2);
  short* t3 = (short*)carve((size_t)BL * E3 * 2);          // [t1a | t1b | z]
  short* qy_bf = (short*)carve((size_t)BL * KE * 2);
  short* hP_bf = (short*)carve((size_t)B * L * K * L * 2); // scores; later r=relu(y@WdT)
  short* r_bf = hP_bf;
  short* wd_bf = (short*)carve((size_t)KE * KE * 2);
  short* wq_all = (short*)carve((size_t)D * KE * E * 2);
  short* woT_all = (short*)carve((size_t)D * E * KE * 2);
  short* Bcat1 = (short*)carve((size_t)D * 2 * E * E * 2); // [wtT; wtc], ld E
  short* Bcat2 = (short*)carve((size_t)D * E * E3 * 2);    // [wtcT | wt | wu], ld 3E
  short* embed_bf = (short*)carve((size_t)G * E * 2);
  short* WemT_bf = (short*)carve((size_t)E * E * 2);
  short* Wkc_bf = (short*)carve((size_t)KN * E * E * 2);
  short* gram_bf = (short*)carve((size_t)B * E * E * 2);
  short* xx_bf = (short*)carve((size_t)B * N * E * 2);
  short* xx2_bf = (short*)carve((size_t)B * N * E * 2);
  short* vv_bf = (short*)carve((size_t)B * N * E * 2);
  short* lptok_bf = (short*)carve((size_t)BLM * E * 2);

  // ---- up-front conversions ----
  cvt(stream, embed, embed_bf, (long)G * E);
  cvt(stream, Wkc, Wkc_bf, (long)KN * E * E);
  cvtT2(stream, Wem, WemT_bf, E, E, E, E, 0, 0, 1);
  cvt(stream, Wq, wq_all, (long)D * KE * E);
  cvtT2(stream, Wo, woT_all, KE, E, E, KE, (long)KE * E, (long)E * KE, D);
  // Bcat1 = [wtT ; wtc] (NT B-operand for [roll+1 @ wt | roll-1 @ wtcT])
  cvtT2(stream, Wt, Bcat1, E, E, E, E, (long)E * E, (long)2 * E * E, D);
  cvt2(stream, Wtc, Bcat1 + (size_t)E * E, E, E, E, E, (long)E * E, (long)2 * E * E, D);
  // Bcat2 = [wtcT | wt | wu], ld 3E (NT B-operand for t3 @ [wtc; wtT; wuT])
  cvtT2(stream, Wtc, Bcat2, E, E, E, E3, (long)E * E, (long)E * E3, D);
  cvt2(stream, Wt, Bcat2 + E, E, E, E, E3, (long)E * E, (long)E * E3, D);
  cvt2(stream, Wu, Bcat2 + 2 * E, E, E, E, E3, (long)E * E, (long)E * E3, D);

  // z = norm(embed[masked]); xsa = z; t3 z-slot filled
  embed_norm_kernel<<<BL, E, 0, stream>>>(masked, embed, xsa, xsa_bf, t3, E);
  cvtT2(stream, xsa, xsaT_bf, L, E, E, L, (long)L * E, (long)E * L, B);

  for (int d = 0; d < D; d++) {
    const float* btl = bt + (size_t)d * E;
    cvt(stream, Wd + (size_t)d * KE * KE, wd_bf, (long)KE * KE);
    // t3[:,0:512] = [relu(roll(xsa,+1)@wt) | relu(roll(xsa,-1)@wtcT)]
    bgemm(stream, xsa_bf, E, 0, Bcat1 + (size_t)d * 2 * E * E, E, 0,
          t3, E3, 0, BL, 2 * E, E, 1, 1.f, nullptr, 1, 1, -1, +1, E, L);
    // xsad = t3 @ [wtc; wtT; wuT] + bt   (fp32)
    bgemm(stream, t3, E3, 0, Bcat2 + (size_t)d * E * E3, E3, 0,
          xsad, E, 0, BL, E, E3, 1, 1.f, btl, 0, 0, 0, 0, 0, L);
    // q = xsa @ wq^T
    bgemm(stream, xsa_bf, E, 0, wq_all + (size_t)d * KE * E, E, 0,
          qy_bf, KE, 0, BL, KE, E, 1, 1.f, nullptr, 0, 1, 0, 0, 0, L);
    // h = q . xsa^T / sqrt(E), batched over B
    bgemm(stream, qy_bf, E, (long)L * KE, xsa_bf, E, (long)L * E,
          hP_bf, L, (long)L * K * L, L * K, L, E, B, inv_sqrt_e, nullptr, 0, 1, 0, 0, 0, L);
    softmax_bf_kernel<<<B * L * K / 4, 256, 0, stream>>>(hP_bf);
    // y = P @ xsa
    bgemm(stream, hP_bf, L, (long)L * K * L, xsaT_bf, L, (long)E * L,
          qy_bf, E, (long)L * KE, L * K, E, L, B, 1.f, nullptr, 0, 1, 0, 0, 0, L);
    // r = relu(y @ wd^T)
    bgemm(stream, qy_bf, KE, 0, wd_bf, KE, 0, r_bf, KE, 0, BL, KE, KE, 1,
          1.f, nullptr, 1, 1, 0, 0, 0, L);
    // xid = r @ wo (fp32)
    bgemm(stream, r_bf, KE, 0, woT_all + (size_t)d * E * KE, KE, 0,
          xid, E, 0, BL, E, KE, 1, 1.f, nullptr, 0, 0, 0, 0, 0, L);
    addnorm_kernel<<<BL, E, 0, stream>>>(xsad, xid, xsa, xsa_bf, E);
    cvtT2(stream, xsa, xsaT_bf, L, E, E, L, (long)L * E, (long)E * L, B);
  }

  // ---- head ----
  gather_kernel<<<BLM, E, 0, stream>>>(xsa, mask, unmasked, lptok_bf, tgt, L, LM, E);
  bgemm(stream, xsaT_bf, L, (long)E * L, xsaT_bf, L, (long)E * L,
        gram_bf, E, (long)E * E, E, E, L, B, 1.f, nullptr, 0, 1, 0, 0, 0, L);
  bgemm(stream, lptok_bf, E, 0, Wkc_bf, E, 0, xx_bf, KN * E, 0, BLM, KN * E, E, 1,
        1.f, bkc, 0, 1, 0, 0, 0, L);
  bgemm(stream, xx_bf, E, (long)N * E, gram_bf, E, (long)E * E,
        xx2_bf, E, (long)N * E, N, E, E, B, 1.f, nullptr, 0, 1, 0, 0, 0, L);
  bgemm(stream, xx2_bf, E, 0, WemT_bf, E, 0, vv_bf, E, 0, B * N, E, E, 1,
        1.f, nullptr, 0, 1, 0, 0, 0, L);
  head_stats_kernel<<<dim3(nch, (B * N) / 128), 256, 0, stream>>>(vv_bf, embed_bf, stM, stS, E, nch);
  lse_reduce_kernel<<<B * N, 256, 0, stream>>>(stM, stS, lse, nch);
  logit_tgt_kernel<<<B * N, E, 0, stream>>>(vv_bf, embed_bf, tgt, lt, E, N, KN, LM);
  final_kernel<<<B, LM, 0, stream>>>(lt, lse, (float*)d_out, LM, KN);
}

// Round 5
// 946.914 us; speedup vs baseline: 8.4610x; 1.3347x over previous
//
#include <hip/hip_runtime.h>
#include <hip/hip_bf16.h>
#include <math.h>

typedef __bf16 bf16x8 __attribute__((ext_vector_type(8)));
typedef float floatx4 __attribute__((ext_vector_type(4)));

__device__ __forceinline__ short f2b(float f) {
  __hip_bfloat16 h = __float2bfloat16(f);
  return *reinterpret_cast<short*>(&h);
}
__device__ __forceinline__ float b2f(short s) {
  unsigned u = ((unsigned)(unsigned short)s) << 16;
  float f;
  __builtin_memcpy(&f, &u, 4);
  return f;
}

// async global->LDS, 16B per lane; lds base must be wave-uniform
__device__ __forceinline__ void gl2lds16(const void* g, void* l) {
  __builtin_amdgcn_global_load_lds((__attribute__((address_space(1))) const void*)g,
                                   (__attribute__((address_space(3))) void*)l, 16, 0, 0);
}

// ---------------- block reduction helper ----------------
__device__ __forceinline__ float block_sum(float v, float* sdata) {
#pragma unroll
  for (int o = 32; o > 0; o >>= 1) v += __shfl_down(v, o, 64);
  __syncthreads();
  int lane = threadIdx.x & 63, wid = threadIdx.x >> 6;
  if (lane == 0) sdata[wid] = v;
  __syncthreads();
  float s = 0.f;
  int nw = blockDim.x >> 6;
  for (int i = 0; i < nw; i++) s += sdata[i];
  return s;
}

// ---------------- conversion kernels ----------------
__global__ void cvt_kernel(const float* __restrict__ src, short* __restrict__ dst, long n4) {
  long i = (long)blockIdx.x * blockDim.x + threadIdx.x;
  if (i < n4) {
    float4 v = ((const float4*)src)[i];
    short4 o;
    o.x = f2b(v.x); o.y = f2b(v.y); o.z = f2b(v.z); o.w = f2b(v.w);
    ((short4*)dst)[i] = o;
  }
}

// dst[r*ldD + c] = bf16(src[r*ldS + c]); grid (C/32, R/32, nb), block (32,8)
__global__ void cvt2_kernel(const float* __restrict__ src, short* __restrict__ dst,
                            int ldS, int ldD, long sS, long sD) {
  src += (size_t)blockIdx.z * sS;
  dst += (size_t)blockIdx.z * sD;
  int c = blockIdx.x * 32 + threadIdx.x;
  int r0 = blockIdx.y * 32 + threadIdx.y;
#pragma unroll
  for (int i = 0; i < 32; i += 8)
    dst[(size_t)(r0 + i) * ldD + c] = f2b(src[(size_t)(r0 + i) * ldS + c]);
}

// dst[c*ldD + r] = bf16(src[r*ldS + c]); grid (C/32, R/32, nb), block (32,8)
__global__ void cvtT2_kernel(const float* __restrict__ src, short* __restrict__ dst,
                             int ldS, int ldD, long sS, long sD) {
  src += (size_t)blockIdx.z * sS;
  dst += (size_t)blockIdx.z * sD;
  __shared__ float tile[32][33];
  int r0 = blockIdx.y * 32, c0 = blockIdx.x * 32;
  int tx = threadIdx.x, ty = threadIdx.y;
#pragma unroll
  for (int i = 0; i < 32; i += 8)
    tile[ty + i][tx] = src[(size_t)(r0 + ty + i) * ldS + c0 + tx];
  __syncthreads();
#pragma unroll
  for (int i = 0; i < 32; i += 8)
    dst[(size_t)(c0 + ty + i) * ldD + r0 + tx] = f2b(tile[tx][ty + i]);
}

// ---------------- embed gather + norm; fills xsa, xsa_bf, xsaT_bf, z-slot of t3 -------
__global__ void embed_norm_kernel(const int* __restrict__ masked,
                                  const float* __restrict__ embed,
                                  float* __restrict__ xsa, short* __restrict__ xsa_bf,
                                  short* __restrict__ xsaT_bf, short* __restrict__ t3,
                                  int E, int L) {
  int row = blockIdx.x;
  int g = masked[row];
  __shared__ float sdata[8];
  float x = embed[(size_t)g * E + threadIdx.x];
  float mean = block_sum(x, sdata) / E;
  float d = x - mean;
  float var = block_sum(d * d, sdata) / (E - 1);
  float val = x / (1.0f + sqrtf(var));
  size_t off = (size_t)row * E + threadIdx.x;
  xsa[off] = val;
  short b = f2b(val);
  xsa_bf[off] = b;
  t3[(size_t)row * 3 * E + 2 * E + threadIdx.x] = b;
  int bb = row / L, l = row - bb * L;
  xsaT_bf[((size_t)bb * E + threadIdx.x) * L + l] = b;
}

// ---------------- bf16 MFMA GEMM (NT), async dbuf, XOR swizzle, tiled ----------------
// C[m,n] = alpha*sum_k A[m,k]*B[n,k] [+bias[n]] [relu]; BMxBN tile, BK=64, 4 waves 2x2.
// A-row roll: shift = (n0 < nsplit ? shiftA : shiftB) applied per-batch of Lroll rows.
template <int BM, int BN, int OUT_BF16>
__global__ __launch_bounds__(256) void bgemm_kernel(
    const short* __restrict__ A, int lda, long sA,
    const short* __restrict__ B, int ldb, long sB,
    void* __restrict__ Cv, int ldc, long sC,
    int Ksz, float alpha, const float* __restrict__ bias,
    int relu, int shiftA, int shiftB, int nsplit, int Lroll) {
  constexpr int WM = BM / 2, WN = BN / 2;
  constexpr int MT = WM / 16, NT = WN / 16;
  constexpr int NCH = (BM + BN) * 8;  // 16B chunks per K-tile
  constexpr int LPT = NCH / 256;      // chunk-groups per thread
  A += (size_t)blockIdx.z * sA;
  B += (size_t)blockIdx.z * sB;
  float* Cf = (float*)Cv + (size_t)blockIdx.z * sC;
  short* Cb = (short*)Cv + (size_t)blockIdx.z * sC;
  int m0 = blockIdx.y * BM, n0 = blockIdx.x * BN;
  int shift = (n0 < nsplit) ? shiftA : shiftB;
  __shared__ short S[2][(BM + BN) * 64];
  int tid = threadIdx.x, lane = tid & 63, w = tid >> 6;
  int wm = (w & 1) * WM, wn = (w >> 1) * WN;
  int ml = lane & 15, q4 = lane >> 4, sw = ml & 7;

  const short* src[LPT];
#pragma unroll
  for (int i = 0; i < LPT; i++) {
    int q = i * 256 + w * 64 + lane;
    if (q < BM * 8) {
      int m = q >> 3, cl = q & 7, cs = cl ^ (m & 7);
      int mg = m0 + m;
      if (shift != 0) {
        int bb = mg / Lroll, l = mg - bb * Lroll;
        l = (l + shift + Lroll) % Lroll;
        mg = bb * Lroll + l;
      }
      src[i] = A + (size_t)mg * lda + cs * 8;
    } else {
      int qb = q - BM * 8;
      int n = qb >> 3, cl = qb & 7, cs = cl ^ (n & 7);
      src[i] = B + (size_t)(n0 + n) * ldb + cs * 8;
    }
  }
  // prologue: stage tile 0
#pragma unroll
  for (int i = 0; i < LPT; i++)
    gl2lds16(src[i], &S[0][(i * 256 + w * 64) * 8]);
  floatx4 acc[MT][NT] = {};
  int nT = Ksz >> 6;
  for (int t = 0; t < nT; t++) {
    __syncthreads();  // drains vmcnt: tile t resident; all waves done with t-1
    int cur = t & 1;
    if (t + 1 < nT) {
      int nxt = cur ^ 1, ko = (t + 1) * 64;
#pragma unroll
      for (int i = 0; i < LPT; i++)
        gl2lds16(src[i] + ko, &S[nxt][(i * 256 + w * 64) * 8]);
    }
#pragma unroll
    for (int kk = 0; kk < 2; kk++) {
      int j = kk * 4 + q4;
      bf16x8 af[MT], bg[NT];
#pragma unroll
      for (int mt = 0; mt < MT; mt++) {
        int r = wm + mt * 16 + ml;
        af[mt] = *reinterpret_cast<const bf16x8*>(&S[cur][r * 64 + (j ^ sw) * 8]);
      }
#pragma unroll
      for (int nt = 0; nt < NT; nt++) {
        int r = wn + nt * 16 + ml;
        bg[nt] = *reinterpret_cast<const bf16x8*>(&S[cur][BM * 64 + r * 64 + (j ^ sw) * 8]);
      }
#pragma unroll
      for (int mt = 0; mt < MT; mt++)
#pragma unroll
        for (int nt = 0; nt < NT; nt++)
          acc[mt][nt] = __builtin_amdgcn_mfma_f32_16x16x32_bf16(af[mt], bg[nt], acc[mt][nt], 0, 0, 0);
    }
  }
#pragma unroll
  for (int mt = 0; mt < MT; mt++)
#pragma unroll
    for (int nt = 0; nt < NT; nt++) {
      floatx4 v = acc[mt][nt];
#pragma unroll
      for (int r = 0; r < 4; r++) {
        int grow = m0 + wm + mt * 16 + q4 * 4 + r;
        int gcol = n0 + wn + nt * 16 + ml;
        float x = alpha * v[r];
        if (bias) x += bias[gcol];
        if (relu) x = fmaxf(x, 0.f);
        if (OUT_BF16)
          Cb[(size_t)grow * ldc + gcol] = f2b(x);
        else
          Cf[(size_t)grow * ldc + gcol] = x;
      }
    }
}

// ---------------- wave-per-row softmax, rows of 512 bf16 ----------------
__global__ void softmax_bf_kernel(short* __restrict__ h) {
  int lane = threadIdx.x & 63;
  size_t row = (size_t)blockIdx.x * 4 + (threadIdx.x >> 6);
  short* p = h + row * 512 + lane * 8;
  int4 raw = *(const int4*)p;
  short sh[8];
  __builtin_memcpy(sh, &raw, 16);
  float v[8];
  float m = -INFINITY;
#pragma unroll
  for (int i = 0; i < 8; i++) {
    v[i] = b2f(sh[i]);
    m = fmaxf(m, v[i]);
  }
#pragma unroll
  for (int o = 1; o < 64; o <<= 1) m = fmaxf(m, __shfl_xor(m, o, 64));
  float s = 0.f;
#pragma unroll
  for (int i = 0; i < 8; i++) {
    v[i] = expf(v[i] - m);
    s += v[i];
  }
#pragma unroll
  for (int o = 1; o < 64; o <<= 1) s += __shfl_xor(s, o, 64);
  float inv = 1.f / s;
#pragma unroll
  for (int i = 0; i < 8; i++) sh[i] = f2b(v[i] * inv);
  __builtin_memcpy(&raw, sh, 16);
  *(int4*)p = raw;
}

// ------- xsad=norm(xsad+xid); xsa=norm(xsa+0.05*xsad); write xsa fp32/bf16/bf16-T -----
__global__ void addnorm_kernel(const float* __restrict__ xsad,
                               const float* __restrict__ xid,
                               float* __restrict__ xsa, short* __restrict__ xsa_bf,
                               short* __restrict__ xsaT_bf, int E, int L) {
  int row = blockIdx.x, t = threadIdx.x;
  __shared__ float sdata[8];
  size_t off = (size_t)row * E + t;
  float s1 = xsad[off] + xid[off];
  float mean = block_sum(s1, sdata) / E;
  float d = s1 - mean;
  float var = block_sum(d * d, sdata) / (E - 1);
  float n1 = s1 / (1.f + sqrtf(var));
  float t2 = xsa[off] + 0.05f * n1;
  float mean2 = block_sum(t2, sdata) / E;
  float d2 = t2 - mean2;
  float var2 = block_sum(d2 * d2, sdata) / (E - 1);
  float res = t2 / (1.f + sqrtf(var2));
  xsa[off] = res;
  short b = f2b(res);
  xsa_bf[off] = b;
  int bb = row / L, l = row - bb * L;
  xsaT_bf[((size_t)bb * E + t) * L + l] = b;
}

// ---------------- gather masked positions (bf16) + targets ----------------
__global__ void gather_kernel(const float* __restrict__ xsa, const int* __restrict__ mask,
                              const int* __restrict__ unmasked,
                              short* __restrict__ lptok_bf, int* __restrict__ tgt,
                              int L, int LM, int E) {
  int bi = blockIdx.x;
  int b = bi / LM;
  int pos = mask[bi];
  float v = xsa[((size_t)b * L + pos) * E + threadIdx.x];
  lptok_bf[(size_t)bi * E + threadIdx.x] = f2b(v);
  if (threadIdx.x == 0) tgt[bi] = unmasked[b * L + pos];
}

// ---------------- head: MFMA logits + per-(row,128-chunk) max/sumexp ----------------
__global__ __launch_bounds__(256) void head_stats_kernel(
    const short* __restrict__ V, const short* __restrict__ Eb,
    float* __restrict__ stM, float* __restrict__ stS, int Ksz, int nch) {
  int m0 = blockIdx.y * 128, n0 = blockIdx.x * 128;
  __shared__ short As[2][8192];
  __shared__ short Bs[2][8192];
  int tid = threadIdx.x, lane = tid & 63, w = tid >> 6;
  int wm = (w & 1) * 64, wn = (w >> 1) * 64;
  int ml = lane & 15, q4 = lane >> 4, sw = ml & 7;
  const short* aSrc[4];
  const short* bSrc[4];
#pragma unroll
  for (int i = 0; i < 4; i++) {
    int q = i * 256 + w * 64 + lane;
    int m = q >> 3, cl = q & 7;
    int cs = cl ^ (m & 7);
    aSrc[i] = V + (size_t)(m0 + m) * Ksz + cs * 8;
    bSrc[i] = Eb + (size_t)(n0 + m) * Ksz + cs * 8;
  }
#pragma unroll
  for (int i = 0; i < 4; i++) {
    gl2lds16(aSrc[i], &As[0][(i * 256 + w * 64) * 8]);
    gl2lds16(bSrc[i], &Bs[0][(i * 256 + w * 64) * 8]);
  }
  floatx4 acc[4][4] = {};
  int nT = Ksz >> 6;
  for (int t = 0; t < nT; t++) {
    __syncthreads();
    int cur = t & 1;
    if (t + 1 < nT) {
      int nxt = cur ^ 1, ko = (t + 1) * 64;
#pragma unroll
      for (int i = 0; i < 4; i++) {
        gl2lds16(aSrc[i] + ko, &As[nxt][(i * 256 + w * 64) * 8]);
        gl2lds16(bSrc[i] + ko, &Bs[nxt][(i * 256 + w * 64) * 8]);
      }
    }
#pragma unroll
    for (int kk = 0; kk < 2; kk++) {
      int j = kk * 4 + q4;
      bf16x8 af[4], bg[4];
#pragma unroll
      for (int mt = 0; mt < 4; mt++) {
        int r = wm + mt * 16 + ml;
        af[mt] = *reinterpret_cast<const bf16x8*>(&As[cur][r * 64 + (j ^ sw) * 8]);
      }
#pragma unroll
      for (int nt = 0; nt < 4; nt++) {
        int r = wn + nt * 16 + ml;
        bg[nt] = *reinterpret_cast<const bf16x8*>(&Bs[cur][r * 64 + (j ^ sw) * 8]);
      }
#pragma unroll
      for (int mt = 0; mt < 4; mt++)
#pragma unroll
        for (int nt = 0; nt < 4; nt++)
          acc[mt][nt] = __builtin_amdgcn_mfma_f32_16x16x32_bf16(af[mt], bg[nt], acc[mt][nt], 0, 0, 0);
    }
  }
  __syncthreads();
  float (*sred)[2] = (float (*)[2]) & As[0][0];
  float (*sred2)[2] = (float (*)[2]) & Bs[0][0];
  float mx[4][4];
#pragma unroll
  for (int mt = 0; mt < 4; mt++)
#pragma unroll
    for (int r = 0; r < 4; r++)
      mx[mt][r] = fmaxf(fmaxf(acc[mt][0][r], acc[mt][1][r]), fmaxf(acc[mt][2][r], acc[mt][3][r]));
#pragma unroll
  for (int off = 1; off < 16; off <<= 1)
#pragma unroll
    for (int mt = 0; mt < 4; mt++)
#pragma unroll
      for (int r = 0; r < 4; r++) mx[mt][r] = fmaxf(mx[mt][r], __shfl_xor(mx[mt][r], off, 64));
  if (ml == 0)
#pragma unroll
    for (int mt = 0; mt < 4; mt++)
#pragma unroll
      for (int r = 0; r < 4; r++) sred[wm + mt * 16 + q4 * 4 + r][w >> 1] = mx[mt][r];
  __syncthreads();
  float sm[4][4];
#pragma unroll
  for (int mt = 0; mt < 4; mt++)
#pragma unroll
    for (int r = 0; r < 4; r++) {
      int row = wm + mt * 16 + q4 * 4 + r;
      float fm = fmaxf(sred[row][0], sred[row][1]);
      float s = 0.f;
#pragma unroll
      for (int nt = 0; nt < 4; nt++) s += expf(acc[mt][nt][r] - fm);
      sm[mt][r] = s;
    }
#pragma unroll
  for (int off = 1; off < 16; off <<= 1)
#pragma unroll
    for (int mt = 0; mt < 4; mt++)
#pragma unroll
      for (int r = 0; r < 4; r++) sm[mt][r] += __shfl_xor(sm[mt][r], off, 64);
  if (ml == 0)
#pragma unroll
    for (int mt = 0; mt < 4; mt++)
#pragma unroll
      for (int r = 0; r < 4; r++) sred2[wm + mt * 16 + q4 * 4 + r][w >> 1] = sm[mt][r];
  __syncthreads();
  if (tid < 128) {
    float fm = fmaxf(sred[tid][0], sred[tid][1]);
    stM[(size_t)(m0 + tid) * nch + blockIdx.x] = fm;
    stS[(size_t)(m0 + tid) * nch + blockIdx.x] = sred2[tid][0] + sred2[tid][1];
  }
}

// ---------------- combine chunk stats -> lse per row ----------------
__global__ void lse_reduce_kernel(const float* __restrict__ statsM,
                                  const float* __restrict__ statsS,
                                  float* __restrict__ lse, int nch) {
  int row = blockIdx.x, t = threadIdx.x;
  float m = -INFINITY, s = 0.f;
  for (int c = t; c < nch; c += blockDim.x) {
    float cm = statsM[(size_t)row * nch + c];
    float cs = statsS[(size_t)row * nch + c];
    float M = fmaxf(m, cm);
    s = s * expf(m - M) + cs * expf(cm - M);
    m = M;
  }
  __shared__ float sm[256], ss[256];
  sm[t] = m;
  ss[t] = s;
  __syncthreads();
  for (int o = 128; o > 0; o >>= 1) {
    if (t < o) {
      float m2 = sm[t + o], s2 = ss[t + o];
      float M = fmaxf(sm[t], m2);
      float sc = ss[t] * expf(sm[t] - M) + s2 * expf(m2 - M);
      sm[t] = M;
      ss[t] = sc;
    }
    __syncthreads();
  }
  if (t == 0) lse[row] = sm[0] + logf(ss[0]);
}

// ---------------- logit at target ----------------
__global__ void logit_tgt_kernel(const short* __restrict__ V, const short* __restrict__ Eb,
                                 const int* __restrict__ tgt, float* __restrict__ lt,
                                 int E, int Nn, int KN, int LM) {
  int row = blockIdx.x;
  int b = row / Nn;
  int i = (row - b * Nn) / KN;
  int g = tgt[b * LM + i];
  __shared__ float sdata[8];
  float v = b2f(V[(size_t)row * E + threadIdx.x]) * b2f(Eb[(size_t)g * E + threadIdx.x]);
  float s = block_sum(v, sdata);
  if (threadIdx.x == 0) lt[row] = s;
}

// ---------------- final ----------------
__global__ void final_kernel(const float* __restrict__ lt, const float* __restrict__ lse,
                             float* __restrict__ out, int LM, int KN) {
  int b = blockIdx.x, i = threadIdx.x;
  int base = (b * LM + i) * KN;
  float m = -INFINITY;
  for (int k = 0; k < KN; k++) m = fmaxf(m, lt[base + k] - lse[base + k]);
  float s = 0.f;
  for (int k = 0; k < KN; k++) s += expf(lt[base + k] - lse[base + k] - m);
  float cent = m + logf(s) - logf((float)KN);
#pragma unroll
  for (int o = 32; o > 0; o >>= 1) cent += __shfl_down(cent, o, 64);
  if (i == 0) out[b] = -cent / LM;
}

// ---------------- host dispatchers ----------------
// cfg: 0 = 128x128, 1 = 128x64, 2 = 64x64
static inline void bgemm(hipStream_t st, int cfg, const short* A, int lda, long sA,
                         const short* B, int ldb, long sB,
                         void* C, int ldc, long sC, int M, int N, int Ksz, int nb,
                         float alpha, const float* bias, int relu, int out_bf16,
                         int shiftA, int shiftB, int nsplit, int Lroll) {
  dim3 block(256);
  if (cfg == 0) {
    dim3 grid(N / 128, M / 128, nb);
    if (out_bf16)
      bgemm_kernel<128, 128, 1><<<grid, block, 0, st>>>(A, lda, sA, B, ldb, sB, C, ldc, sC, Ksz, alpha, bias, relu, shiftA, shiftB, nsplit, Lroll);
    else
      bgemm_kernel<128, 128, 0><<<grid, block, 0, st>>>(A, lda, sA, B, ldb, sB, C, ldc, sC, Ksz, alpha, bias, relu, shiftA, shiftB, nsplit, Lroll);
  } else if (cfg == 1) {
    dim3 grid(N / 64, M / 128, nb);
    if (out_bf16)
      bgemm_kernel<128, 64, 1><<<grid, block, 0, st>>>(A, lda, sA, B, ldb, sB, C, ldc, sC, Ksz, alpha, bias, relu, shiftA, shiftB, nsplit, Lroll);
    else
      bgemm_kernel<128, 64, 0><<<grid, block, 0, st>>>(A, lda, sA, B, ldb, sB, C, ldc, sC, Ksz, alpha, bias, relu, shiftA, shiftB, nsplit, Lroll);
  } else {
    dim3 grid(N / 64, M / 64, nb);
    if (out_bf16)
      bgemm_kernel<64, 64, 1><<<grid, block, 0, st>>>(A, lda, sA, B, ldb, sB, C, ldc, sC, Ksz, alpha, bias, relu, shiftA, shiftB, nsplit, Lroll);
    else
      bgemm_kernel<64, 64, 0><<<grid, block, 0, st>>>(A, lda, sA, B, ldb, sB, C, ldc, sC, Ksz, alpha, bias, relu, shiftA, shiftB, nsplit, Lroll);
  }
}

static inline void cvt(hipStream_t st, const float* src, short* dst, long n) {
  long n4 = n / 4;
  cvt_kernel<<<(int)((n4 + 255) / 256), 256, 0, st>>>(src, dst, n4);
}

static inline void cvt2(hipStream_t st, const float* src, short* dst, int R, int C,
                        int ldS, int ldD, long sS, long sD, int nb) {
  dim3 grid(C / 32, R / 32, nb), block(32, 8);
  cvt2_kernel<<<grid, block, 0, st>>>(src, dst, ldS, ldD, sS, sD);
}

static inline void cvtT2(hipStream_t st, const float* src, short* dst, int R, int C,
                         int ldS, int ldD, long sS, long sD, int nb) {
  dim3 grid(C / 32, R / 32, nb), block(32, 8);
  cvtT2_kernel<<<grid, block, 0, st>>>(src, dst, ldS, ldD, sS, sD);
}

extern "C" void kernel_launch(void* const* d_in, const int* in_sizes, int n_in,
                              void* d_out, int out_size, void* d_ws, size_t ws_size,
                              hipStream_t stream) {
  const int* masked = (const int*)d_in[0];
  const int* unmasked = (const int*)d_in[1];
  const int* mask = (const int*)d_in[2];
  const float* embed = (const float*)d_in[3];
  const float* Wt = (const float*)d_in[4];
  const float* bt = (const float*)d_in[5];
  const float* Wtc = (const float*)d_in[6];
  const float* Wq = (const float*)d_in[7];
  const float* Wd = (const float*)d_in[8];
  const float* Wo = (const float*)d_in[9];
  const float* Wu = (const float*)d_in[10];
  const float* Wem = (const float*)d_in[11];
  const float* Wkc = (const float*)d_in[12];
  const float* bkc = (const float*)d_in[13];

  const int B = out_size;                  // 4
  const int BL = in_sizes[0];              // 2048
  const int L = BL / B;                    // 512
  const int BLM = in_sizes[2];             // 256
  const int LM = BLM / B;                  // 64
  const int E = in_sizes[4] / in_sizes[5]; // 256
  const int D = in_sizes[5] / E;           // 6
  const int G = in_sizes[3] / E;           // 32000
  const int K = in_sizes[7] / (D * E * E); // 8
  const int KN = in_sizes[12] / (E * E);   // 4
  const int KE = K * E;                    // 2048
  const int N = LM * KN;                   // 256
  const float inv_sqrt_e = 1.0f / sqrtf((float)E);
  const int nch = G / 128;                 // 250
  const int E3 = 3 * E;                    // 768

  // ---- workspace carve ----
  char* base = (char*)d_ws;
  size_t off = 0;
  auto carve = [&](size_t bytes) {
    char* p = base + off;
    off += (bytes + 255) & ~(size_t)255;
    return p;
  };
  float* xsa = (float*)carve((size_t)BL * E * 4);
  float* xsad = (float*)carve((size_t)BL * E * 4);
  float* xid = (float*)carve((size_t)BL * E * 4);
  float* stM = (float*)carve((size_t)B * N * nch * 4);
  float* stS = (float*)carve((size_t)B * N * nch * 4);
  float* lse = (float*)carve((size_t)B * N * 4);
  float* lt = (float*)carve((size_t)B * N * 4);
  int* tgt = (int*)carve((size_t)B * LM * 4);
  short* xsa_bf = (short*)carve((size_t)BL * E * 2);
  short* xsaT_bf = (short*)carve((size_t)B * E * L * 2);
  short* t3 = (short*)carve((size_t)BL * E3 * 2);          // [t1a | t1b | z]
  short* qy_bf = (short*)carve((size_t)BL * KE * 2);
  short* hP_bf = (short*)carve((size_t)B * L * K * L * 2); // scores; later r=relu(y@WdT)
  short* r_bf = hP_bf;
  short* wd_all = (short*)carve((size_t)D * KE * KE * 2);
  short* wq_all = (short*)carve((size_t)D * KE * E * 2);
  short* woT_all = (short*)carve((size_t)D * E * KE * 2);
  short* Bcat1 = (short*)carve((size_t)D * 2 * E * E * 2); // [wtT; wtc], ld E
  short* Bcat2 = (short*)carve((size_t)D * E * E3 * 2);    // [wtcT | wt | wu], ld 3E
  short* embed_bf = (short*)carve((size_t)G * E * 2);
  short* WemT_bf = (short*)carve((size_t)E * E * 2);
  short* Wkc_bf = (short*)carve((size_t)KN * E * E * 2);
  short* gram_bf = (short*)carve((size_t)B * E * E * 2);
  short* xx_bf = (short*)carve((size_t)B * N * E * 2);
  short* xx2_bf = (short*)carve((size_t)B * N * E * 2);
  short* vv_bf = (short*)carve((size_t)B * N * E * 2);
  short* lptok_bf = (short*)carve((size_t)BLM * E * 2);

  // ---- up-front conversions ----
  cvt(stream, embed, embed_bf, (long)G * E);
  cvt(stream, Wd, wd_all, (long)D * KE * KE);
  cvt(stream, Wq, wq_all, (long)D * KE * E);
  cvt(stream, Wkc, Wkc_bf, (long)KN * E * E);
  cvtT2(stream, Wem, WemT_bf, E, E, E, E, 0, 0, 1);
  cvtT2(stream, Wo, woT_all, KE, E, E, KE, (long)KE * E, (long)E * KE, D);
  // Bcat1 = [wtT ; wtc] (NT B-operand for [roll+1 @ wt | roll-1 @ wtcT])
  cvtT2(stream, Wt, Bcat1, E, E, E, E, (long)E * E, (long)2 * E * E, D);
  cvt2(stream, Wtc, Bcat1 + (size_t)E * E, E, E, E, E, (long)E * E, (long)2 * E * E, D);
  // Bcat2 = [wtcT | wt | wu], ld 3E (NT B-operand for t3 @ [wtc; wtT; wuT])
  cvtT2(stream, Wtc, Bcat2, E, E, E, E3, (long)E * E, (long)E * E3, D);
  cvt2(stream, Wt, Bcat2 + E, E, E, E, E3, (long)E * E, (long)E * E3, D);
  cvt2(stream, Wu, Bcat2 + 2 * E, E, E, E, E3, (long)E * E, (long)E * E3, D);

  // z = norm(embed[masked]); xsa = z (+bf16, +transposed, +t3 z-slot)
  embed_norm_kernel<<<BL, E, 0, stream>>>(masked, embed, xsa, xsa_bf, xsaT_bf, t3, E, L);

  for (int d = 0; d < D; d++) {
    const float* btl = bt + (size_t)d * E;
    // t3[:,0:512] = [relu(roll(xsa,+1)@wt) | relu(roll(xsa,-1)@wtcT)]
    bgemm(stream, 2, xsa_bf, E, 0, Bcat1 + (size_t)d * 2 * E * E, E, 0,
          t3, E3, 0, BL, 2 * E, E, 1, 1.f, nullptr, 1, 1, -1, +1, E, L);
    // xsad = t3 @ [wtc; wtT; wuT] + bt   (fp32)
    bgemm(stream, 2, t3, E3, 0, Bcat2 + (size_t)d * E * E3, E3, 0,
          xsad, E, 0, BL, E, E3, 1, 1.f, btl, 0, 0, 0, 0, 0, L);
    // q = xsa @ wq^T
    bgemm(stream, 1, xsa_bf, E, 0, wq_all + (size_t)d * KE * E, E, 0,
          qy_bf, KE, 0, BL, KE, E, 1, 1.f, nullptr, 0, 1, 0, 0, 0, L);
    // h = q . xsa^T / sqrt(E), batched over B
    bgemm(stream, 0, qy_bf, E, (long)L * KE, xsa_bf, E, (long)L * E,
          hP_bf, L, (long)L * K * L, L * K, L, E, B, inv_sqrt_e, nullptr, 0, 1, 0, 0, 0, L);
    softmax_bf_kernel<<<B * L * K / 4, 256, 0, stream>>>(hP_bf);
    // y = P @ xsa
    bgemm(stream, 1, hP_bf, L, (long)L * K * L, xsaT_bf, L, (long)E * L,
          qy_bf, E, (long)L * KE, L * K, E, L, B, 1.f, nullptr, 0, 1, 0, 0, 0, L);
    // r = relu(y @ wd^T)
    bgemm(stream, 1, qy_bf, KE, 0, wd_all + (size_t)d * KE * KE, KE, 0,
          r_bf, KE, 0, BL, KE, KE, 1, 1.f, nullptr, 1, 1, 0, 0, 0, L);
    // xid = r @ wo (fp32)
    bgemm(stream, 2, r_bf, KE, 0, woT_all + (size_t)d * E * KE, KE, 0,
          xid, E, 0, BL, E, KE, 1, 1.f, nullptr, 0, 0, 0, 0, 0, L);
    addnorm_kernel<<<BL, E, 0, stream>>>(xsad, xid, xsa, xsa_bf, xsaT_bf, E, L);
  }

  // ---- head ----
  gather_kernel<<<BLM, E, 0, stream>>>(xsa, mask, unmasked, lptok_bf, tgt, L, LM, E);
  bgemm(stream, 2, xsaT_bf, L, (long)E * L, xsaT_bf, L, (long)E * L,
        gram_bf, E, (long)E * E, E, E, L, B, 1.f, nullptr, 0, 1, 0, 0, 0, L);
  bgemm(stream, 2, lptok_bf, E, 0, Wkc_bf, E, 0, xx_bf, KN * E, 0, BLM, KN * E, E, 1,
        1.f, bkc, 0, 1, 0, 0, 0, L);
  bgemm(stream, 2, xx_bf, E, (long)N * E, gram_bf, E, (long)E * E,
        xx2_bf, E, (long)N * E, N, E, E, B, 1.f, nullptr, 0, 1, 0, 0, 0, L);
  bgemm(stream, 2, xx2_bf, E, 0, WemT_bf, E, 0, vv_bf, E, 0, B * N, E, E, 1,
        1.f, nullptr, 0, 1, 0, 0, 0, L);
  head_stats_kernel<<<dim3(nch, (B * N) / 128), 256, 0, stream>>>(vv_bf, embed_bf, stM, stS, E, nch);
  lse_reduce_kernel<<<B * N, 256, 0, stream>>>(stM, stS, lse, nch);
  logit_tgt_kernel<<<B * N, E, 0, stream>>>(vv_bf, embed_bf, tgt, lt, E, N, KN, LM);
  final_kernel<<<B, LM, 0, stream>>>(lt, lse, (float*)d_out, LM, KN);
}